// Round 1
// baseline (1910.600 us; speedup 1.0000x reference)
//
#include <hip/hip_runtime.h>
#include <math.h>

#define B_GRAPHS 50
#define NPG0     2000
#define EPG      12000
#define F_IN_C   256
#define NHID     128
#define N0       (B_GRAPHS * NPG0)   // 100000
#define NE       (B_GRAPHS * EPG)    // 600000

static inline int cdiv(int a, int b) { return (a + b - 1) / b; }

// ---------------- utility fills ----------------
__global__ void k_fill_f32(float* __restrict__ p, float v, int n) {
    int i = blockIdx.x * 256 + threadIdx.x;
    if (i < n) p[i] = v;
}
__global__ void k_fill_i32(int* __restrict__ p, int v, int n) {
    int i = blockIdx.x * 256 + threadIdx.x;
    if (i < n) p[i] = v;
}

// ---------------- edge init ----------------
__global__ void k_init_edges(const int* __restrict__ ei, int* __restrict__ esrc,
                             int* __restrict__ edst, float* __restrict__ ew) {
    int e = blockIdx.x * 256 + threadIdx.x;
    if (e < NE) { esrc[e] = ei[e]; edst[e] = ei[NE + e]; ew[e] = 1.0f; }
}

// ---------------- GEMM: H[N x 128] = Xin[N x F] @ W[F x 128] ----------------
#define GBM 64
#define GBK 32
__global__ __launch_bounds__(256) void k_gemm(const float* __restrict__ Xin,
                                              const float* __restrict__ W,
                                              float* __restrict__ H, int N, int F) {
    __shared__ float sA[GBK][GBM];    // [k][m]
    __shared__ float sB[GBK][NHID];   // [k][n]
    const int tid = threadIdx.x;
    const int m0 = blockIdx.x * GBM;
    const int tn = (tid & 15) << 3;   // 16 threads cover 128 cols, 8 each
    const int tm = (tid >> 4) << 2;   // 16 thread-rows cover 64 rows, 4 each

    float acc[4][8];
#pragma unroll
    for (int i = 0; i < 4; ++i)
#pragma unroll
        for (int j = 0; j < 8; ++j) acc[i][j] = 0.f;

    const int Fq = F >> 2;
    const float4* X4 = (const float4*)Xin;
    const float4* W4 = (const float4*)W;

    for (int k0 = 0; k0 < F; k0 += GBK) {
        // A tile: 64 x 32 floats = 512 float4, transposed into sA[k][m]
#pragma unroll
        for (int t = tid; t < GBM * (GBK / 4); t += 256) {
            int m = t >> 3, kq = t & 7;
            int row = m0 + m;
            float4 v = make_float4(0.f, 0.f, 0.f, 0.f);
            if (row < N) v = X4[(size_t)row * Fq + (k0 >> 2) + kq];
            sA[kq * 4 + 0][m] = v.x; sA[kq * 4 + 1][m] = v.y;
            sA[kq * 4 + 2][m] = v.z; sA[kq * 4 + 3][m] = v.w;
        }
        // B tile: 32 x 128 floats = 1024 float4/4
#pragma unroll
        for (int t = tid; t < GBK * (NHID / 4); t += 256) {
            int kk = t >> 5, nq = t & 31;
            float4 v = W4[(size_t)(k0 + kk) * (NHID / 4) + nq];
            *(float4*)&sB[kk][nq * 4] = v;
        }
        __syncthreads();
#pragma unroll
        for (int kk = 0; kk < GBK; ++kk) {
            const float4 a  = *(const float4*)&sA[kk][tm];
            const float4 b0 = *(const float4*)&sB[kk][tn];
            const float4 b1 = *(const float4*)&sB[kk][tn + 4];
            const float av[4] = {a.x, a.y, a.z, a.w};
            const float bv[8] = {b0.x, b0.y, b0.z, b0.w, b1.x, b1.y, b1.z, b1.w};
#pragma unroll
            for (int i = 0; i < 4; ++i)
#pragma unroll
                for (int j = 0; j < 8; ++j)
                    acc[i][j] = fmaf(av[i], bv[j], acc[i][j]);
        }
        __syncthreads();
    }
#pragma unroll
    for (int i = 0; i < 4; ++i) {
        int row = m0 + tm + i;
        if (row < N) {
            float4 o0 = make_float4(acc[i][0], acc[i][1], acc[i][2], acc[i][3]);
            float4 o1 = make_float4(acc[i][4], acc[i][5], acc[i][6], acc[i][7]);
            *(float4*)&H[(size_t)row * NHID + tn]     = o0;
            *(float4*)&H[(size_t)row * NHID + tn + 4] = o1;
        }
    }
}

// ---------------- degree (init to 1.0 beforehand) ----------------
__global__ void k_deg(const int* __restrict__ edst, const float* __restrict__ ew,
                      float* __restrict__ deg) {
    int e = blockIdx.x * 256 + threadIdx.x;
    if (e < NE) {
        float we = ew[e];
        if (we > 0.f) atomicAdd(&deg[edst[e]], we);
    }
}

// ---------------- CSR build ----------------
__global__ void k_count(const int* __restrict__ edst, const float* __restrict__ ew,
                        int* __restrict__ cnt) {
    int e = blockIdx.x * 256 + threadIdx.x;
    if (e < NE) {
        if (ew[e] > 0.f) atomicAdd(&cnt[edst[e]], 1);
    }
}

__global__ __launch_bounds__(256) void k_scan(const int* __restrict__ cnt,
                                              int* __restrict__ offs,
                                              int* __restrict__ cursor, int npg) {
    __shared__ int ch[256];
    int b = blockIdx.x, tid = threadIdx.x;
    int per = (npg + 255) >> 8;
    int base = b * npg;
    int s0 = tid * per;
    int s1 = s0 + per; if (s1 > npg) s1 = npg; if (s0 > npg) s0 = npg;
    int s = 0;
    for (int i = s0; i < s1; ++i) s += cnt[base + i];
    ch[tid] = s;
    __syncthreads();
    for (int d = 1; d < 256; d <<= 1) {
        int t = ch[tid] + ((tid >= d) ? ch[tid - d] : 0);
        __syncthreads();
        ch[tid] = t;
        __syncthreads();
    }
    int run = b * EPG + ch[tid] - s;   // exclusive offset with per-graph base
    for (int i = s0; i < s1; ++i) {
        offs[base + i] = run; cursor[base + i] = run;
        run += cnt[base + i];
    }
}

__global__ void k_fill_csr(const int* __restrict__ esrc, const int* __restrict__ edst,
                           const float* __restrict__ ew, const float* __restrict__ deg,
                           int* __restrict__ cursor, int* __restrict__ csr_src,
                           float* __restrict__ csr_norm) {
    int e = blockIdx.x * 256 + threadIdx.x;
    if (e < NE) {
        float we = ew[e];
        if (we > 0.f) {
            int sN = esrc[e], d = edst[e];
            int pos = atomicAdd(&cursor[d], 1);
            csr_src[pos] = sN;
            csr_norm[pos] = we * rsqrtf(deg[sN]) * rsqrtf(deg[d]);
        }
    }
}

// ---------------- main aggregation: X = relu(agg + H/deg + b) ----------------
__global__ __launch_bounds__(128) void k_agg(const float* __restrict__ H,
                                             const int* __restrict__ csr_src,
                                             const float* __restrict__ csr_norm,
                                             const int* __restrict__ offs,
                                             const int* __restrict__ cnt,
                                             const float* __restrict__ deg,
                                             const float* __restrict__ bias,
                                             float* __restrict__ X) {
    int node = blockIdx.x;
    int f = threadIdx.x;
    int s = offs[node], c = cnt[node];
    float acc = 0.f;
    for (int e = s; e < s + c; ++e) {
        int u = csr_src[e];
        acc = fmaf(H[(size_t)u * NHID + f], csr_norm[e], acc);
    }
    float v = acc + H[(size_t)node * NHID + f] / deg[node] + bias[f];
    X[(size_t)node * NHID + f] = fmaxf(v, 0.f);
}

// ---------------- score projection: hs[i] = dot(X[i,:], Ws) ----------------
__global__ __launch_bounds__(256) void k_hs(const float* __restrict__ X,
                                            const float* __restrict__ Ws,
                                            float* __restrict__ hs, int N) {
    int node = blockIdx.x * 4 + (threadIdx.x >> 6);
    int lane = threadIdx.x & 63;
    if (node >= N) return;
    const float* row = X + (size_t)node * NHID;
    float s = row[lane] * Ws[lane] + row[lane + 64] * Ws[lane + 64];
#pragma unroll
    for (int off = 32; off > 0; off >>= 1) s += __shfl_down(s, off, 64);
    if (lane == 0) hs[node] = s;
}

// ---------------- score aggregation (scalar GCN) ----------------
__global__ void k_score(const float* __restrict__ hs, const int* __restrict__ csr_src,
                        const float* __restrict__ csr_norm, const int* __restrict__ offs,
                        const int* __restrict__ cnt, const float* __restrict__ deg,
                        const float* __restrict__ bs, float* __restrict__ score, int N) {
    int i = blockIdx.x * 256 + threadIdx.x;
    if (i >= N) return;
    int s = offs[i], c = cnt[i];
    float a = 0.f;
    for (int e = s; e < s + c; ++e) a = fmaf(hs[csr_src[e]], csr_norm[e], a);
    score[i] = a + hs[i] / deg[i] + bs[0];
}

// ---------------- per-graph top-k via bitonic sort (desc score, asc idx) ----------------
__global__ __launch_bounds__(1024) void k_topk(const float* __restrict__ score,
                                               int* __restrict__ mapping,
                                               int* __restrict__ perm,
                                               float* __restrict__ gate,
                                               int npg, int k) {
    __shared__ float ss[2048];
    __shared__ int   si[2048];
    int b = blockIdx.x, tid = threadIdx.x;
    for (int i = tid; i < 2048; i += 1024) {
        if (i < npg) { ss[i] = score[b * npg + i]; si[i] = i; }
        else         { ss[i] = -__builtin_inff();  si[i] = i; }
    }
    __syncthreads();
    for (int size = 2; size <= 2048; size <<= 1) {
        for (int stride = size >> 1; stride > 0; stride >>= 1) {
            int t = tid;
            int i = ((t & ~(stride - 1)) << 1) | (t & (stride - 1));
            int j = i | stride;
            float sa = ss[i], sb = ss[j];
            int   ia = si[i], ib = si[j];
            bool b_before_a = (sb > sa) || (sb == sa && ib < ia); // strict total order, descending
            bool forward = ((i & size) == 0);
            bool doswap = forward ? b_before_a : !b_before_a;
            if (doswap) { ss[i] = sb; ss[j] = sa; si[i] = ib; si[j] = ia; }
            __syncthreads();
        }
    }
    for (int j = tid; j < k; j += 1024) {
        int old_local = si[j];
        int oldg = b * npg + old_local;
        int newg = b * k + j;
        perm[newg] = oldg;
        mapping[oldg] = newg;
        gate[newg] = tanhf(ss[j]);
    }
}

// ---------------- pooled features: XP[new] = X[old] * tanh(score[old]) ----------------
__global__ void k_pool(const float* __restrict__ X, const float* __restrict__ gate,
                       const int* __restrict__ perm, float* __restrict__ XP, int total) {
    int idx = blockIdx.x * 256 + threadIdx.x;
    if (idx >= total) return;
    int j = idx >> 7, f = idx & 127;
    int old = perm[j];
    XP[idx] = X[(size_t)old * NHID + f] * gate[j];
}

// ---------------- edge remap (in place) ----------------
__global__ void k_remap(int* __restrict__ esrc, int* __restrict__ edst,
                        float* __restrict__ ew, const int* __restrict__ mapping) {
    int e = blockIdx.x * 256 + threadIdx.x;
    if (e >= NE) return;
    int sN = esrc[e], d = edst[e];
    float we = ew[e];
    int ns = mapping[sN], nd = mapping[d];
    bool valid = (ns >= 0) && (nd >= 0) && (we > 0.f);
    esrc[e] = valid ? ns : 0;
    edst[e] = valid ? nd : 0;
    ew[e] = valid ? we : 0.f;
}

// ---------------- readout: accum[b][0:128]+=max, [128:256]+=mean ----------------
__global__ __launch_bounds__(128) void k_readout(const float* __restrict__ XP,
                                                 float* __restrict__ accum, int k) {
    int b = blockIdx.x, f = threadIdx.x;
    const float* base = XP + (size_t)b * k * NHID;
    float mx = -__builtin_inff(), sm = 0.f;
    for (int j = 0; j < k; ++j) {
        float v = base[(size_t)j * NHID + f];
        mx = fmaxf(mx, v);
        sm += v;
    }
    accum[b * 256 + f]       += mx;
    accum[b * 256 + 128 + f] += sm / (float)k;
}

// ---------------- final: out = relu(accum @ Wl + bl) ----------------
__global__ __launch_bounds__(128) void k_final(const float* __restrict__ accum,
                                               const float* __restrict__ Wl,
                                               const float* __restrict__ bl,
                                               float* __restrict__ out) {
    __shared__ float a[256];
    int b = blockIdx.x, o = threadIdx.x;
    for (int i = o; i < 256; i += 128) a[i] = accum[b * 256 + i];
    __syncthreads();
    float s = bl[o];
    for (int i = 0; i < 256; ++i) s = fmaf(a[i], Wl[i * NHID + o], s);
    out[b * NHID + o] = fmaxf(s, 0.f);
}

extern "C" void kernel_launch(void* const* d_in, const int* in_sizes, int n_in,
                              void* d_out, int out_size, void* d_ws, size_t ws_size,
                              hipStream_t stream) {
    const float* x0 = (const float*)d_in[0];
    const float* Wm[3] = {(const float*)d_in[1], (const float*)d_in[5], (const float*)d_in[9]};
    const float* bm[3] = {(const float*)d_in[2], (const float*)d_in[6], (const float*)d_in[10]};
    const float* Wsc[3] = {(const float*)d_in[3], (const float*)d_in[7], (const float*)d_in[11]};
    const float* bsc[3] = {(const float*)d_in[4], (const float*)d_in[8], (const float*)d_in[12]};
    const float* Wl = (const float*)d_in[13];
    const float* bl = (const float*)d_in[14];
    const int*   ei = (const int*)d_in[15];
    float* out = (float*)d_out;

    // workspace layout (all fp32/int32, 16B-aligned offsets)
    float* bufA   = (float*)d_ws;                       // N0*128
    float* bufB   = bufA + (size_t)N0 * NHID;           // N0*128
    float* deg    = bufB + (size_t)N0 * NHID;           // N0
    float* hs     = deg + N0;                           // N0
    float* score  = hs + N0;                            // N0
    float* gate   = score + N0;                         // N0
    float* accum  = gate + N0;                          // B*256
    int*   cnt    = (int*)(accum + B_GRAPHS * 256);     // N0
    int*   offs   = cnt + N0;                           // N0
    int*   cursor = offs + N0;                          // N0
    int*   mapping= cursor + N0;                        // N0
    int*   perm   = mapping + N0;                       // N0 (>= B*k)
    int*   esrc   = perm + N0;                          // NE
    int*   edst   = esrc + NE;                          // NE
    float* ew     = (float*)(edst + NE);                // NE
    int*   csr_src= (int*)(ew + NE);                    // NE
    float* csr_norm = (float*)(csr_src + NE);           // NE

    const int EG = cdiv(NE, 256);

    k_init_edges<<<EG, 256, 0, stream>>>(ei, esrc, edst, ew);
    k_fill_f32<<<cdiv(B_GRAPHS * 256, 256), 256, 0, stream>>>(accum, 0.f, B_GRAPHS * 256);

    int npg = NPG0;
    const float* xin = x0;
    int F = F_IN_C;
    float* Hbuf = bufA; float* Xbuf = bufB; float* XPbuf = bufA;

    for (int layer = 0; layer < 3; ++layer) {
        int N = B_GRAPHS * npg;
        int k = (npg * 4) / 5;   // ceil(0.8*n) exact for 2000/1600/1280
        int NG = cdiv(N, 256);

        k_fill_f32<<<NG, 256, 0, stream>>>(deg, 1.0f, N);
        k_fill_i32<<<NG, 256, 0, stream>>>(cnt, 0, N);
        if (layer < 2) k_fill_i32<<<NG, 256, 0, stream>>>(mapping, -1, N);

        k_gemm<<<cdiv(N, GBM), 256, 0, stream>>>(xin, Wm[layer], Hbuf, N, F);
        k_deg<<<EG, 256, 0, stream>>>(edst, ew, deg);
        k_count<<<EG, 256, 0, stream>>>(edst, ew, cnt);
        k_scan<<<B_GRAPHS, 256, 0, stream>>>(cnt, offs, cursor, npg);
        k_fill_csr<<<EG, 256, 0, stream>>>(esrc, edst, ew, deg, cursor, csr_src, csr_norm);
        k_agg<<<N, 128, 0, stream>>>(Hbuf, csr_src, csr_norm, offs, cnt, deg, bm[layer], Xbuf);
        k_hs<<<cdiv(N, 4), 256, 0, stream>>>(Xbuf, Wsc[layer], hs, N);
        k_score<<<NG, 256, 0, stream>>>(hs, csr_src, csr_norm, offs, cnt, deg, bsc[layer], score, N);
        k_topk<<<B_GRAPHS, 1024, 0, stream>>>(score, mapping, perm, gate, npg, k);
        k_pool<<<cdiv(B_GRAPHS * k * NHID, 256), 256, 0, stream>>>(Xbuf, gate, perm, XPbuf, B_GRAPHS * k * NHID);
        if (layer < 2) k_remap<<<EG, 256, 0, stream>>>(esrc, edst, ew, mapping);
        k_readout<<<B_GRAPHS, 128, 0, stream>>>(XPbuf, accum, k);

        xin = XPbuf;
        npg = k;
        F = NHID;
        if (layer == 0) { Hbuf = bufB; Xbuf = bufA; XPbuf = bufB; }
        else            { Hbuf = bufA; Xbuf = bufB; XPbuf = bufA; }
    }

    k_final<<<B_GRAPHS, 128, 0, stream>>>(accum, Wl, bl, out);
}

// Round 2
// 955.549 us; speedup vs baseline: 1.9995x; 1.9995x over previous
//
#include <hip/hip_runtime.h>
#include <math.h>

#define B_GRAPHS 50
#define NPG0     2000
#define EPG      12000
#define F_IN_C   256
#define NHID     128
#define N0       (B_GRAPHS * NPG0)   // 100000
#define NE       (B_GRAPHS * EPG)    // 600000
#define RSEG     16                  // readout segments per graph

static inline int cdiv(int a, int b) { return (a + b - 1) / b; }

// ---------------- utility fills ----------------
__global__ void k_fill_f32(float* __restrict__ p, float v, int n) {
    int i = blockIdx.x * 256 + threadIdx.x;
    if (i < n) p[i] = v;
}
__global__ void k_fill_i32(int* __restrict__ p, int v, int n) {
    int i = blockIdx.x * 256 + threadIdx.x;
    if (i < n) p[i] = v;
}

// ---------------- edge init ----------------
__global__ void k_init_edges(const int* __restrict__ ei, int* __restrict__ esrc,
                             int* __restrict__ edst, float* __restrict__ ew) {
    int e = blockIdx.x * 256 + threadIdx.x;
    if (e < NE) { esrc[e] = ei[e]; edst[e] = ei[NE + e]; ew[e] = 1.0f; }
}

// ---------------- GEMM: H[N x 128] = Xin[N x F] @ W[F x 128] ----------------
#define GBM 64
#define GBK 32
__global__ __launch_bounds__(256) void k_gemm(const float* __restrict__ Xin,
                                              const float* __restrict__ W,
                                              float* __restrict__ H, int N, int F) {
    __shared__ float sA[GBK][GBM];    // [k][m]
    __shared__ float sB[GBK][NHID];   // [k][n]
    const int tid = threadIdx.x;
    const int m0 = blockIdx.x * GBM;
    const int tn = (tid & 15) << 3;   // 16 threads cover 128 cols, 8 each
    const int tm = (tid >> 4) << 2;   // 16 thread-rows cover 64 rows, 4 each

    float acc[4][8];
#pragma unroll
    for (int i = 0; i < 4; ++i)
#pragma unroll
        for (int j = 0; j < 8; ++j) acc[i][j] = 0.f;

    const int Fq = F >> 2;
    const float4* X4 = (const float4*)Xin;
    const float4* W4 = (const float4*)W;

    for (int k0 = 0; k0 < F; k0 += GBK) {
#pragma unroll
        for (int t = tid; t < GBM * (GBK / 4); t += 256) {
            int m = t >> 3, kq = t & 7;
            int row = m0 + m;
            float4 v = make_float4(0.f, 0.f, 0.f, 0.f);
            if (row < N) v = X4[(size_t)row * Fq + (k0 >> 2) + kq];
            sA[kq * 4 + 0][m] = v.x; sA[kq * 4 + 1][m] = v.y;
            sA[kq * 4 + 2][m] = v.z; sA[kq * 4 + 3][m] = v.w;
        }
#pragma unroll
        for (int t = tid; t < GBK * (NHID / 4); t += 256) {
            int kk = t >> 5, nq = t & 31;
            float4 v = W4[(size_t)(k0 + kk) * (NHID / 4) + nq];
            *(float4*)&sB[kk][nq * 4] = v;
        }
        __syncthreads();
#pragma unroll
        for (int kk = 0; kk < GBK; ++kk) {
            const float4 a  = *(const float4*)&sA[kk][tm];
            const float4 b0 = *(const float4*)&sB[kk][tn];
            const float4 b1 = *(const float4*)&sB[kk][tn + 4];
            const float av[4] = {a.x, a.y, a.z, a.w};
            const float bv[8] = {b0.x, b0.y, b0.z, b0.w, b1.x, b1.y, b1.z, b1.w};
#pragma unroll
            for (int i = 0; i < 4; ++i)
#pragma unroll
                for (int j = 0; j < 8; ++j)
                    acc[i][j] = fmaf(av[i], bv[j], acc[i][j]);
        }
        __syncthreads();
    }
#pragma unroll
    for (int i = 0; i < 4; ++i) {
        int row = m0 + tm + i;
        if (row < N) {
            float4 o0 = make_float4(acc[i][0], acc[i][1], acc[i][2], acc[i][3]);
            float4 o1 = make_float4(acc[i][4], acc[i][5], acc[i][6], acc[i][7]);
            *(float4*)&H[(size_t)row * NHID + tn]     = o0;
            *(float4*)&H[(size_t)row * NHID + tn + 4] = o1;
        }
    }
}

// ---------------- degree (init to 1.0 beforehand) ----------------
__global__ void k_deg(const int* __restrict__ edst, const float* __restrict__ ew,
                      float* __restrict__ deg) {
    int e = blockIdx.x * 256 + threadIdx.x;
    if (e < NE) {
        float we = ew[e];
        if (we > 0.f) atomicAdd(&deg[edst[e]], we);
    }
}

// ---------------- CSR build ----------------
__global__ void k_count(const int* __restrict__ edst, const float* __restrict__ ew,
                        int* __restrict__ cnt) {
    int e = blockIdx.x * 256 + threadIdx.x;
    if (e < NE) {
        if (ew[e] > 0.f) atomicAdd(&cnt[edst[e]], 1);
    }
}

__global__ __launch_bounds__(256) void k_scan(const int* __restrict__ cnt,
                                              int* __restrict__ offs,
                                              int* __restrict__ cursor, int npg) {
    __shared__ int ch[256];
    int b = blockIdx.x, tid = threadIdx.x;
    int per = (npg + 255) >> 8;
    int base = b * npg;
    int s0 = tid * per;
    int s1 = s0 + per; if (s1 > npg) s1 = npg; if (s0 > npg) s0 = npg;
    int s = 0;
    for (int i = s0; i < s1; ++i) s += cnt[base + i];
    ch[tid] = s;
    __syncthreads();
    for (int d = 1; d < 256; d <<= 1) {
        int t = ch[tid] + ((tid >= d) ? ch[tid - d] : 0);
        __syncthreads();
        ch[tid] = t;
        __syncthreads();
    }
    int run = b * EPG + ch[tid] - s;   // exclusive offset with per-graph base
    for (int i = s0; i < s1; ++i) {
        offs[base + i] = run; cursor[base + i] = run;
        run += cnt[base + i];
    }
}

__global__ void k_fill_csr(const int* __restrict__ esrc, const int* __restrict__ edst,
                           const float* __restrict__ ew, const float* __restrict__ deg,
                           int* __restrict__ cursor, int* __restrict__ csr_src,
                           float* __restrict__ csr_norm) {
    int e = blockIdx.x * 256 + threadIdx.x;
    if (e < NE) {
        float we = ew[e];
        if (we > 0.f) {
            int sN = esrc[e], d = edst[e];
            int pos = atomicAdd(&cursor[d], 1);
            csr_src[pos] = sN;
            csr_norm[pos] = we * rsqrtf(deg[sN]) * rsqrtf(deg[d]);
        }
    }
}

// ---------------- main aggregation: X = relu(agg + H/deg + b) ----------------
__global__ __launch_bounds__(128) void k_agg(const float* __restrict__ H,
                                             const int* __restrict__ csr_src,
                                             const float* __restrict__ csr_norm,
                                             const int* __restrict__ offs,
                                             const int* __restrict__ cnt,
                                             const float* __restrict__ deg,
                                             const float* __restrict__ bias,
                                             float* __restrict__ X) {
    int node = blockIdx.x;
    int f = threadIdx.x;
    int s = offs[node], c = cnt[node];
    float acc = 0.f;
    for (int e = s; e < s + c; ++e) {
        int u = csr_src[e];
        acc = fmaf(H[(size_t)u * NHID + f], csr_norm[e], acc);
    }
    float v = acc + H[(size_t)node * NHID + f] / deg[node] + bias[f];
    X[(size_t)node * NHID + f] = fmaxf(v, 0.f);
}

// ---------------- score projection: hs[i] = dot(X[i,:], Ws) ----------------
__global__ __launch_bounds__(256) void k_hs(const float* __restrict__ X,
                                            const float* __restrict__ Ws,
                                            float* __restrict__ hs, int N) {
    int node = blockIdx.x * 4 + (threadIdx.x >> 6);
    int lane = threadIdx.x & 63;
    if (node >= N) return;
    const float* row = X + (size_t)node * NHID;
    float s = row[lane] * Ws[lane] + row[lane + 64] * Ws[lane + 64];
#pragma unroll
    for (int off = 32; off > 0; off >>= 1) s += __shfl_down(s, off, 64);
    if (lane == 0) hs[node] = s;
}

// ---------------- score aggregation (scalar GCN) ----------------
__global__ void k_score(const float* __restrict__ hs, const int* __restrict__ csr_src,
                        const float* __restrict__ csr_norm, const int* __restrict__ offs,
                        const int* __restrict__ cnt, const float* __restrict__ deg,
                        const float* __restrict__ bs, float* __restrict__ score, int N) {
    int i = blockIdx.x * 256 + threadIdx.x;
    if (i >= N) return;
    int s = offs[i], c = cnt[i];
    float a = 0.f;
    for (int e = s; e < s + c; ++e) a = fmaf(hs[csr_src[e]], csr_norm[e], a);
    score[i] = a + hs[i] / deg[i] + bs[0];
}

// ---------------- per-graph top-k via bitonic sort (desc score, asc idx) ----------------
__global__ __launch_bounds__(1024) void k_topk(const float* __restrict__ score,
                                               int* __restrict__ mapping,
                                               int* __restrict__ perm,
                                               float* __restrict__ gate,
                                               int npg, int k) {
    __shared__ float ss[2048];
    __shared__ int   si[2048];
    int b = blockIdx.x, tid = threadIdx.x;
    for (int i = tid; i < 2048; i += 1024) {
        if (i < npg) { ss[i] = score[b * npg + i]; si[i] = i; }
        else         { ss[i] = -__builtin_inff();  si[i] = i; }
    }
    __syncthreads();
    for (int size = 2; size <= 2048; size <<= 1) {
        for (int stride = size >> 1; stride > 0; stride >>= 1) {
            int t = tid;
            int i = ((t & ~(stride - 1)) << 1) | (t & (stride - 1));
            int j = i | stride;
            float sa = ss[i], sb = ss[j];
            int   ia = si[i], ib = si[j];
            bool b_before_a = (sb > sa) || (sb == sa && ib < ia); // strict total order, descending
            bool forward = ((i & size) == 0);
            bool doswap = forward ? b_before_a : !b_before_a;
            if (doswap) { ss[i] = sb; ss[j] = sa; si[i] = ib; si[j] = ia; }
            __syncthreads();
        }
    }
    for (int j = tid; j < k; j += 1024) {
        int old_local = si[j];
        int oldg = b * npg + old_local;
        int newg = b * k + j;
        perm[newg] = oldg;
        mapping[oldg] = newg;
        gate[newg] = tanhf(ss[j]);
    }
}

// ---------------- fused pool + partial readout ----------------
// grid (RSEG, B), 128 threads. XP[new] = X[old]*gate; per-segment max/sum partials.
__global__ __launch_bounds__(128) void k_pool_readout(const float* __restrict__ X,
                                                      const float* __restrict__ gate,
                                                      const int* __restrict__ perm,
                                                      float* __restrict__ XP,
                                                      float* __restrict__ pmax,
                                                      float* __restrict__ psum, int k) {
    int s = blockIdx.x, b = blockIdx.y, f = threadIdx.x;
    int j0 = (k * s) / RSEG, j1 = (k * (s + 1)) / RSEG;
    float mx = -__builtin_inff(), sm = 0.f;
    for (int j = j0; j < j1; ++j) {
        int g = b * k + j;
        int old = perm[g];
        float v = X[(size_t)old * NHID + f] * gate[g];
        XP[(size_t)g * NHID + f] = v;
        mx = fmaxf(mx, v);
        sm += v;
    }
    pmax[(size_t)(b * RSEG + s) * NHID + f] = mx;
    psum[(size_t)(b * RSEG + s) * NHID + f] = sm;
}

__global__ __launch_bounds__(128) void k_readout_comb(const float* __restrict__ pmax,
                                                      const float* __restrict__ psum,
                                                      float* __restrict__ accum, int k) {
    int b = blockIdx.x, f = threadIdx.x;
    float mx = -__builtin_inff(), sm = 0.f;
#pragma unroll
    for (int s = 0; s < RSEG; ++s) {
        mx = fmaxf(mx, pmax[(size_t)(b * RSEG + s) * NHID + f]);
        sm += psum[(size_t)(b * RSEG + s) * NHID + f];
    }
    accum[b * 256 + f]       += mx;
    accum[b * 256 + 128 + f] += sm / (float)k;
}

// ---------------- edge remap (in place) ----------------
__global__ void k_remap(int* __restrict__ esrc, int* __restrict__ edst,
                        float* __restrict__ ew, const int* __restrict__ mapping) {
    int e = blockIdx.x * 256 + threadIdx.x;
    if (e >= NE) return;
    int sN = esrc[e], d = edst[e];
    float we = ew[e];
    int ns = mapping[sN], nd = mapping[d];
    bool valid = (ns >= 0) && (nd >= 0) && (we > 0.f);
    esrc[e] = valid ? ns : 0;
    edst[e] = valid ? nd : 0;
    ew[e] = valid ? we : 0.f;
}

// ---------------- final: out = relu(accum @ Wl + bl) ----------------
__global__ __launch_bounds__(128) void k_final(const float* __restrict__ accum,
                                               const float* __restrict__ Wl,
                                               const float* __restrict__ bl,
                                               float* __restrict__ out) {
    __shared__ float a[256];
    int b = blockIdx.x, o = threadIdx.x;
    for (int i = o; i < 256; i += 128) a[i] = accum[b * 256 + i];
    __syncthreads();
    float s = bl[o];
    for (int i = 0; i < 256; ++i) s = fmaf(a[i], Wl[i * NHID + o], s);
    out[b * NHID + o] = fmaxf(s, 0.f);
}

extern "C" void kernel_launch(void* const* d_in, const int* in_sizes, int n_in,
                              void* d_out, int out_size, void* d_ws, size_t ws_size,
                              hipStream_t stream) {
    const float* x0 = (const float*)d_in[0];
    const float* Wm[3] = {(const float*)d_in[1], (const float*)d_in[5], (const float*)d_in[9]};
    const float* bm[3] = {(const float*)d_in[2], (const float*)d_in[6], (const float*)d_in[10]};
    const float* Wsc[3] = {(const float*)d_in[3], (const float*)d_in[7], (const float*)d_in[11]};
    const float* bsc[3] = {(const float*)d_in[4], (const float*)d_in[8], (const float*)d_in[12]};
    const float* Wl = (const float*)d_in[13];
    const float* bl = (const float*)d_in[14];
    const int*   ei = (const int*)d_in[15];
    float* out = (float*)d_out;

    // workspace layout
    float* bufA   = (float*)d_ws;                       // N0*128
    float* bufB   = bufA + (size_t)N0 * NHID;           // N0*128
    float* deg    = bufB + (size_t)N0 * NHID;           // N0
    float* hs     = deg + N0;                           // N0
    float* score  = hs + N0;                            // N0
    float* gate   = score + N0;                         // N0
    float* accum  = gate + N0;                          // B*256
    float* pmax   = accum + B_GRAPHS * 256;             // B*RSEG*128
    float* psum   = pmax + B_GRAPHS * RSEG * NHID;      // B*RSEG*128
    int*   cnt    = (int*)(psum + B_GRAPHS * RSEG * NHID); // N0
    int*   offs   = cnt + N0;                           // N0
    int*   cursor = offs + N0;                          // N0
    int*   mapping= cursor + N0;                        // N0
    int*   perm   = mapping + N0;                       // N0 (>= B*k)
    int*   esrc   = perm + N0;                          // NE
    int*   edst   = esrc + NE;                          // NE
    float* ew     = (float*)(edst + NE);                // NE
    int*   csr_src= (int*)(ew + NE);                    // NE
    float* csr_norm = (float*)(csr_src + NE);           // NE

    const int EG = cdiv(NE, 256);

    k_init_edges<<<EG, 256, 0, stream>>>(ei, esrc, edst, ew);
    k_fill_f32<<<cdiv(B_GRAPHS * 256, 256), 256, 0, stream>>>(accum, 0.f, B_GRAPHS * 256);

    int npg = NPG0;
    const float* xin = x0;
    int F = F_IN_C;
    float* Hbuf = bufA; float* Xbuf = bufB; float* XPbuf = bufA;

    for (int layer = 0; layer < 3; ++layer) {
        int N = B_GRAPHS * npg;
        int k = (npg * 4) / 5;   // ceil(0.8*n) exact for 2000/1600/1280
        int NG = cdiv(N, 256);

        k_fill_f32<<<NG, 256, 0, stream>>>(deg, 1.0f, N);
        k_fill_i32<<<NG, 256, 0, stream>>>(cnt, 0, N);
        if (layer < 2) k_fill_i32<<<NG, 256, 0, stream>>>(mapping, -1, N);

        k_gemm<<<cdiv(N, GBM), 256, 0, stream>>>(xin, Wm[layer], Hbuf, N, F);
        k_deg<<<EG, 256, 0, stream>>>(edst, ew, deg);
        k_count<<<EG, 256, 0, stream>>>(edst, ew, cnt);
        k_scan<<<B_GRAPHS, 256, 0, stream>>>(cnt, offs, cursor, npg);
        k_fill_csr<<<EG, 256, 0, stream>>>(esrc, edst, ew, deg, cursor, csr_src, csr_norm);
        k_agg<<<N, 128, 0, stream>>>(Hbuf, csr_src, csr_norm, offs, cnt, deg, bm[layer], Xbuf);
        k_hs<<<cdiv(N, 4), 256, 0, stream>>>(Xbuf, Wsc[layer], hs, N);
        k_score<<<NG, 256, 0, stream>>>(hs, csr_src, csr_norm, offs, cnt, deg, bsc[layer], score, N);
        k_topk<<<B_GRAPHS, 1024, 0, stream>>>(score, mapping, perm, gate, npg, k);
        k_pool_readout<<<dim3(RSEG, B_GRAPHS), 128, 0, stream>>>(Xbuf, gate, perm, XPbuf, pmax, psum, k);
        if (layer < 2) k_remap<<<EG, 256, 0, stream>>>(esrc, edst, ew, mapping);
        k_readout_comb<<<B_GRAPHS, 128, 0, stream>>>(pmax, psum, accum, k);

        xin = XPbuf;
        npg = k;
        F = NHID;
        if (layer == 0) { Hbuf = bufB; Xbuf = bufA; XPbuf = bufB; }
        else            { Hbuf = bufA; Xbuf = bufB; XPbuf = bufA; }
    }

    k_final<<<B_GRAPHS, 128, 0, stream>>>(accum, Wl, bl, out);
}

// Round 3
// 737.548 us; speedup vs baseline: 2.5905x; 1.2956x over previous
//
#include <hip/hip_runtime.h>
#include <math.h>

#define B_GRAPHS 50
#define NPG0     2000
#define EPG      12000
#define F_IN_C   256
#define NHID     128
#define N0       (B_GRAPHS * NPG0)   // 100000
#define NE       (B_GRAPHS * EPG)    // 600000
#define RSEG     16                  // readout segments per graph

typedef _Float16 f16x8 __attribute__((ext_vector_type(8)));
typedef _Float16 f16x2 __attribute__((ext_vector_type(2)));
typedef float    f32x4 __attribute__((ext_vector_type(4)));

static inline int cdiv(int a, int b) { return (a + b - 1) / b; }

// ---------------- utility fills ----------------
__global__ void k_fill_f32(float* __restrict__ p, float v, int n) {
    int i = blockIdx.x * 256 + threadIdx.x;
    if (i < n) p[i] = v;
}
__global__ void k_fill_i32(int* __restrict__ p, int v, int n) {
    int i = blockIdx.x * 256 + threadIdx.x;
    if (i < n) p[i] = v;
}

// ---------------- edge init ----------------
__global__ void k_init_edges(const int* __restrict__ ei, int* __restrict__ esrc,
                             int* __restrict__ edst, float* __restrict__ ew) {
    int e = blockIdx.x * 256 + threadIdx.x;
    if (e < NE) { esrc[e] = ei[e]; edst[e] = ei[NE + e]; ew[e] = 1.0f; }
}

// ---------------- weight convert+transpose: WT[n][k] = (fp16)W[k][n] ----------------
__global__ void k_cvt_wt(const float* __restrict__ W, _Float16* __restrict__ WT, int F) {
    int t = blockIdx.x * 256 + threadIdx.x;
    if (t >= F * 128) return;
    int n = t / F, kk = t - n * F;
    WT[t] = (_Float16)W[(size_t)kk * 128 + n];
}

// ---------------- MFMA GEMM: H[N x 128](fp16) = Xin[N x F] @ W[F x 128] ----------------
// block: 256 threads (4 waves), tile 128 rows x 128 cols, K-step 32.
// LDS staging stride 40 halves (pad 8) -> 2 lanes/bank-group on b128 frag reads (free).
#define LDK  40
#define CPAD 136
template<int FP32IN>
__global__ __launch_bounds__(256) void k_gemm_mfma(const void* __restrict__ Xin,
                                                   const _Float16* __restrict__ WT,
                                                   _Float16* __restrict__ H,
                                                   int N, int F) {
    __shared__ _Float16 smem[17408];      // 34816 B: staging 2*128*40, epilogue 128*136
    _Float16* sA  = smem;                 // [128][LDK]
    _Float16* sBT = smem + 128 * LDK;     // [128][LDK]  (B transposed: [n][k])
    const int tid  = threadIdx.x;
    const int wave = tid >> 6, lane = tid & 63;
    const int quad = lane >> 4, l16 = lane & 15;
    const int m_blk = blockIdx.x * 128;

    f32x4 acc[2][8];
#pragma unroll
    for (int i = 0; i < 2; ++i)
#pragma unroll
        for (int j = 0; j < 8; ++j) acc[i][j] = {0.f, 0.f, 0.f, 0.f};

    const int r  = tid >> 1;              // staging row 0..127
    const int ch = (tid & 1) * 16;        // halves chunk offset 0/16
    const int grow = m_blk + r;
    const int rw = wave * 32;

    for (int k0 = 0; k0 < F; k0 += 32) {
        // ---- stage A (convert fp32->fp16 on the fly for layer 1) ----
        f16x8 a0 = {0,0,0,0,0,0,0,0}, a1 = {0,0,0,0,0,0,0,0};
        if (grow < N) {
            if (FP32IN) {
                const float4* Xr = (const float4*)((const float*)Xin + (size_t)grow * F + k0 + ch);
                float4 f0 = Xr[0], f1 = Xr[1], f2 = Xr[2], f3 = Xr[3];
                a0 = (f16x8){(_Float16)f0.x,(_Float16)f0.y,(_Float16)f0.z,(_Float16)f0.w,
                             (_Float16)f1.x,(_Float16)f1.y,(_Float16)f1.z,(_Float16)f1.w};
                a1 = (f16x8){(_Float16)f2.x,(_Float16)f2.y,(_Float16)f2.z,(_Float16)f2.w,
                             (_Float16)f3.x,(_Float16)f3.y,(_Float16)f3.z,(_Float16)f3.w};
            } else {
                const f16x8* Xr = (const f16x8*)((const _Float16*)Xin + (size_t)grow * F + k0 + ch);
                a0 = Xr[0]; a1 = Xr[1];
            }
        }
        *(f16x8*)&sA[r * LDK + ch]     = a0;
        *(f16x8*)&sA[r * LDK + ch + 8] = a1;
        // ---- stage B^T ----
        {
            const f16x8* Wr = (const f16x8*)(WT + (size_t)r * F + k0 + ch);
            *(f16x8*)&sBT[r * LDK + ch]     = Wr[0];
            *(f16x8*)&sBT[r * LDK + ch + 8] = Wr[1];
        }
        __syncthreads();
        // ---- compute: 2 row-tiles x 8 col-tiles per wave ----
        f16x8 af0 = *(const f16x8*)&sA[(rw + l16) * LDK + quad * 8];
        f16x8 af1 = *(const f16x8*)&sA[(rw + 16 + l16) * LDK + quad * 8];
        f16x8 bf[8];
#pragma unroll
        for (int j = 0; j < 8; ++j)
            bf[j] = *(const f16x8*)&sBT[(j * 16 + l16) * LDK + quad * 8];
#pragma unroll
        for (int j = 0; j < 8; ++j) {
            acc[0][j] = __builtin_amdgcn_mfma_f32_16x16x32_f16(af0, bf[j], acc[0][j], 0, 0, 0);
            acc[1][j] = __builtin_amdgcn_mfma_f32_16x16x32_f16(af1, bf[j], acc[1][j], 0, 0, 0);
        }
        __syncthreads();
    }

    // ---- epilogue: bounce through LDS for coalesced fp16 stores ----
    _Float16* sC = smem;                  // [128][CPAD]
#pragma unroll
    for (int i = 0; i < 2; ++i)
#pragma unroll
        for (int j = 0; j < 8; ++j)
#pragma unroll
            for (int g = 0; g < 4; ++g) {
                int rl = rw + i * 16 + quad * 4 + g;
                int cl = j * 16 + l16;
                sC[rl * CPAD + cl] = (_Float16)acc[i][j][g];
            }
    __syncthreads();
    {
        int rr = tid >> 1;
        int gr = m_blk + rr;
        if (gr < N) {
            _Float16* Hr = H + (size_t)gr * 128 + (tid & 1) * 64;
            const _Float16* Sr = sC + rr * CPAD + (tid & 1) * 64;
#pragma unroll
            for (int c = 0; c < 8; ++c)
                *(f16x8*)&Hr[c * 8] = *(const f16x8*)&Sr[c * 8];
        }
    }
}

// ---------------- CSR build (w is always 0 or 1 -> deg = cnt+1) ----------------
__global__ void k_count(const int* __restrict__ edst, const float* __restrict__ ew,
                        int* __restrict__ cnt) {
    int e = blockIdx.x * 256 + threadIdx.x;
    if (e < NE) {
        if (ew[e] > 0.f) atomicAdd(&cnt[edst[e]], 1);
    }
}

__global__ __launch_bounds__(256) void k_scan(const int* __restrict__ cnt,
                                              int* __restrict__ offs,
                                              int* __restrict__ cursor, int npg) {
    __shared__ int ch[256];
    int b = blockIdx.x, tid = threadIdx.x;
    int per = (npg + 255) >> 8;
    int base = b * npg;
    int s0 = tid * per;
    int s1 = s0 + per; if (s1 > npg) s1 = npg; if (s0 > npg) s0 = npg;
    int s = 0;
    for (int i = s0; i < s1; ++i) s += cnt[base + i];
    ch[tid] = s;
    __syncthreads();
    for (int d = 1; d < 256; d <<= 1) {
        int t = ch[tid] + ((tid >= d) ? ch[tid - d] : 0);
        __syncthreads();
        ch[tid] = t;
        __syncthreads();
    }
    int run = b * EPG + ch[tid] - s;   // exclusive offset with per-graph base
    for (int i = s0; i < s1; ++i) {
        offs[base + i] = run; cursor[base + i] = run;
        run += cnt[base + i];
    }
}

__global__ void k_fill_csr(const int* __restrict__ esrc, const int* __restrict__ edst,
                           const float* __restrict__ ew, const int* __restrict__ cnt,
                           int* __restrict__ cursor, int* __restrict__ csr_src,
                           float* __restrict__ csr_norm) {
    int e = blockIdx.x * 256 + threadIdx.x;
    if (e < NE) {
        if (ew[e] > 0.f) {
            int sN = esrc[e], d = edst[e];
            int pos = atomicAdd(&cursor[d], 1);
            csr_src[pos] = sN;
            csr_norm[pos] = rsqrtf((float)(cnt[sN] + 1)) * rsqrtf((float)(cnt[d] + 1));
        }
    }
}

// -------- aggregation + fused score projection: X = relu(agg + H/deg + b); hs = X.Ws --------
// 4 nodes per 256-thread block; 64 lanes per node, 2 features/lane via half2.
__global__ __launch_bounds__(256) void k_agg(const _Float16* __restrict__ H,
                                             const int* __restrict__ csr_src,
                                             const float* __restrict__ csr_norm,
                                             const int* __restrict__ offs,
                                             const int* __restrict__ cnt,
                                             const float* __restrict__ bias,
                                             const float* __restrict__ Ws,
                                             _Float16* __restrict__ X,
                                             float* __restrict__ hs, int N) {
    int node = blockIdx.x * 4 + (threadIdx.x >> 6);
    int lane = threadIdx.x & 63;
    if (node >= N) return;
    int s = offs[node], c = cnt[node];
    float ax = 0.f, ay = 0.f;
    for (int e = s; e < s + c; ++e) {
        int u = csr_src[e];
        float nrm = csr_norm[e];
        f16x2 h2 = *(const f16x2*)&H[(size_t)u * NHID + lane * 2];
        ax = fmaf((float)h2.x, nrm, ax);
        ay = fmaf((float)h2.y, nrm, ay);
    }
    float invd = 1.0f / (float)(c + 1);
    f16x2 hn = *(const f16x2*)&H[(size_t)node * NHID + lane * 2];
    float vx = fmaxf(ax + (float)hn.x * invd + bias[lane * 2],     0.f);
    float vy = fmaxf(ay + (float)hn.y * invd + bias[lane * 2 + 1], 0.f);
    *(f16x2*)&X[(size_t)node * NHID + lane * 2] = (f16x2){(_Float16)vx, (_Float16)vy};
    float sd = vx * Ws[lane * 2] + vy * Ws[lane * 2 + 1];
#pragma unroll
    for (int off = 32; off > 0; off >>= 1) sd += __shfl_down(sd, off, 64);
    if (lane == 0) hs[node] = sd;
}

// ---------------- score aggregation (scalar GCN) ----------------
__global__ void k_score(const float* __restrict__ hs, const int* __restrict__ csr_src,
                        const float* __restrict__ csr_norm, const int* __restrict__ offs,
                        const int* __restrict__ cnt, const float* __restrict__ bs,
                        float* __restrict__ score, int N) {
    int i = blockIdx.x * 256 + threadIdx.x;
    if (i >= N) return;
    int s = offs[i], c = cnt[i];
    float a = 0.f;
    for (int e = s; e < s + c; ++e) a = fmaf(hs[csr_src[e]], csr_norm[e], a);
    score[i] = a + hs[i] / (float)(c + 1) + bs[0];
}

// ---------------- per-graph top-k via bitonic sort (desc score, asc idx) ----------------
__global__ __launch_bounds__(1024) void k_topk(const float* __restrict__ score,
                                               int* __restrict__ mapping,
                                               int* __restrict__ perm,
                                               float* __restrict__ gate,
                                               int npg, int k) {
    __shared__ float ss[2048];
    __shared__ int   si[2048];
    int b = blockIdx.x, tid = threadIdx.x;
    for (int i = tid; i < 2048; i += 1024) {
        if (i < npg) { ss[i] = score[b * npg + i]; si[i] = i; }
        else         { ss[i] = -__builtin_inff();  si[i] = i; }
    }
    __syncthreads();
    for (int size = 2; size <= 2048; size <<= 1) {
        for (int stride = size >> 1; stride > 0; stride >>= 1) {
            int t = tid;
            int i = ((t & ~(stride - 1)) << 1) | (t & (stride - 1));
            int j = i | stride;
            float sa = ss[i], sb = ss[j];
            int   ia = si[i], ib = si[j];
            bool b_before_a = (sb > sa) || (sb == sa && ib < ia);
            bool forward = ((i & size) == 0);
            bool doswap = forward ? b_before_a : !b_before_a;
            if (doswap) { ss[i] = sb; ss[j] = sa; si[i] = ib; si[j] = ia; }
            __syncthreads();
        }
    }
    for (int j = tid; j < k; j += 1024) {
        int old_local = si[j];
        int oldg = b * npg + old_local;
        int newg = b * k + j;
        perm[newg] = oldg;
        mapping[oldg] = newg;
        gate[newg] = tanhf(ss[j]);
    }
}

// ---------------- fused pool + partial readout ----------------
__global__ __launch_bounds__(128) void k_pool_readout(const _Float16* __restrict__ X,
                                                      const float* __restrict__ gate,
                                                      const int* __restrict__ perm,
                                                      _Float16* __restrict__ XP,
                                                      float* __restrict__ pmax,
                                                      float* __restrict__ psum, int k) {
    int s = blockIdx.x, b = blockIdx.y, f = threadIdx.x;
    int j0 = (k * s) / RSEG, j1 = (k * (s + 1)) / RSEG;
    float mx = -__builtin_inff(), sm = 0.f;
    for (int j = j0; j < j1; ++j) {
        int g = b * k + j;
        int old = perm[g];
        float v = (float)X[(size_t)old * NHID + f] * gate[g];
        XP[(size_t)g * NHID + f] = (_Float16)v;
        mx = fmaxf(mx, v);
        sm += v;
    }
    pmax[(size_t)(b * RSEG + s) * NHID + f] = mx;
    psum[(size_t)(b * RSEG + s) * NHID + f] = sm;
}

__global__ __launch_bounds__(128) void k_readout_comb(const float* __restrict__ pmax,
                                                      const float* __restrict__ psum,
                                                      float* __restrict__ accum, int k) {
    int b = blockIdx.x, f = threadIdx.x;
    float mx = -__builtin_inff(), sm = 0.f;
#pragma unroll
    for (int s = 0; s < RSEG; ++s) {
        mx = fmaxf(mx, pmax[(size_t)(b * RSEG + s) * NHID + f]);
        sm += psum[(size_t)(b * RSEG + s) * NHID + f];
    }
    accum[b * 256 + f]       += mx;
    accum[b * 256 + 128 + f] += sm / (float)k;
}

// ---------------- edge remap (in place) ----------------
__global__ void k_remap(int* __restrict__ esrc, int* __restrict__ edst,
                        float* __restrict__ ew, const int* __restrict__ mapping) {
    int e = blockIdx.x * 256 + threadIdx.x;
    if (e >= NE) return;
    int sN = esrc[e], d = edst[e];
    float we = ew[e];
    int ns = mapping[sN], nd = mapping[d];
    bool valid = (ns >= 0) && (nd >= 0) && (we > 0.f);
    esrc[e] = valid ? ns : 0;
    edst[e] = valid ? nd : 0;
    ew[e] = valid ? we : 0.f;
}

// ---------------- final: out = relu(accum @ Wl + bl) ----------------
__global__ __launch_bounds__(128) void k_final(const float* __restrict__ accum,
                                               const float* __restrict__ Wl,
                                               const float* __restrict__ bl,
                                               float* __restrict__ out) {
    __shared__ float a[256];
    int b = blockIdx.x, o = threadIdx.x;
    for (int i = o; i < 256; i += 128) a[i] = accum[b * 256 + i];
    __syncthreads();
    float s = bl[o];
    for (int i = 0; i < 256; ++i) s = fmaf(a[i], Wl[i * NHID + o], s);
    out[b * NHID + o] = fmaxf(s, 0.f);
}

extern "C" void kernel_launch(void* const* d_in, const int* in_sizes, int n_in,
                              void* d_out, int out_size, void* d_ws, size_t ws_size,
                              hipStream_t stream) {
    const float* x0 = (const float*)d_in[0];
    const float* Wm[3] = {(const float*)d_in[1], (const float*)d_in[5], (const float*)d_in[9]};
    const float* bm[3] = {(const float*)d_in[2], (const float*)d_in[6], (const float*)d_in[10]};
    const float* Wsc[3] = {(const float*)d_in[3], (const float*)d_in[7], (const float*)d_in[11]};
    const float* bsc[3] = {(const float*)d_in[4], (const float*)d_in[8], (const float*)d_in[12]};
    const float* Wl = (const float*)d_in[13];
    const float* bl = (const float*)d_in[14];
    const int*   ei = (const int*)d_in[15];
    float* out = (float*)d_out;

    // workspace layout: fp16 buffers first, then fp32, then int
    _Float16* bufA = (_Float16*)d_ws;                       // N0*128 halves
    _Float16* bufB = bufA + (size_t)N0 * NHID;              // N0*128
    _Float16* WT1  = bufB + (size_t)N0 * NHID;              // 128*256
    _Float16* WT2  = WT1 + 128 * 256;                       // 128*128
    _Float16* WT3  = WT2 + 128 * 128;                       // 128*128
    float* hs     = (float*)(WT3 + 128 * 128);              // N0
    float* score  = hs + N0;                                // N0
    float* gate   = score + N0;                             // N0
    float* accum  = gate + N0;                              // B*256
    float* pmax   = accum + B_GRAPHS * 256;                 // B*RSEG*128
    float* psum   = pmax + B_GRAPHS * RSEG * NHID;          // B*RSEG*128
    int*   cnt    = (int*)(psum + B_GRAPHS * RSEG * NHID);  // N0
    int*   offs   = cnt + N0;                               // N0
    int*   cursor = offs + N0;                              // N0
    int*   mapping= cursor + N0;                            // N0
    int*   perm   = mapping + N0;                           // N0
    int*   esrc   = perm + N0;                              // NE
    int*   edst   = esrc + NE;                              // NE
    float* ew     = (float*)(edst + NE);                    // NE
    int*   csr_src= (int*)(ew + NE);                        // NE
    float* csr_norm = (float*)(csr_src + NE);               // NE

    _Float16* WTs[3] = {WT1, WT2, WT3};
    const int EG = cdiv(NE, 256);

    k_init_edges<<<EG, 256, 0, stream>>>(ei, esrc, edst, ew);
    k_fill_f32<<<cdiv(B_GRAPHS * 256, 256), 256, 0, stream>>>(accum, 0.f, B_GRAPHS * 256);
    k_cvt_wt<<<cdiv(256 * 128, 256), 256, 0, stream>>>(Wm[0], WT1, 256);
    k_cvt_wt<<<cdiv(128 * 128, 256), 256, 0, stream>>>(Wm[1], WT2, 128);
    k_cvt_wt<<<cdiv(128 * 128, 256), 256, 0, stream>>>(Wm[2], WT3, 128);

    int npg = NPG0;
    const void* xin = (const void*)x0;
    int F = F_IN_C;
    _Float16* Hbuf = bufA; _Float16* Xbuf = bufB; _Float16* XPbuf = bufA;

    for (int layer = 0; layer < 3; ++layer) {
        int N = B_GRAPHS * npg;
        int k = (npg * 4) / 5;   // ceil(0.8*n) exact for 2000/1600/1280
        int NG = cdiv(N, 256);

        k_fill_i32<<<NG, 256, 0, stream>>>(cnt, 0, N);
        if (layer < 2) k_fill_i32<<<NG, 256, 0, stream>>>(mapping, -1, N);

        if (layer == 0)
            k_gemm_mfma<1><<<cdiv(N, 128), 256, 0, stream>>>(xin, WTs[layer], Hbuf, N, F);
        else
            k_gemm_mfma<0><<<cdiv(N, 128), 256, 0, stream>>>(xin, WTs[layer], Hbuf, N, F);
        k_count<<<EG, 256, 0, stream>>>(edst, ew, cnt);
        k_scan<<<B_GRAPHS, 256, 0, stream>>>(cnt, offs, cursor, npg);
        k_fill_csr<<<EG, 256, 0, stream>>>(esrc, edst, ew, cnt, cursor, csr_src, csr_norm);
        k_agg<<<cdiv(N, 4), 256, 0, stream>>>(Hbuf, csr_src, csr_norm, offs, cnt, bm[layer],
                                              Wsc[layer], Xbuf, hs, N);
        k_score<<<NG, 256, 0, stream>>>(hs, csr_src, csr_norm, offs, cnt, bsc[layer], score, N);
        k_topk<<<B_GRAPHS, 1024, 0, stream>>>(score, mapping, perm, gate, npg, k);
        k_pool_readout<<<dim3(RSEG, B_GRAPHS), 128, 0, stream>>>(Xbuf, gate, perm, XPbuf, pmax, psum, k);
        if (layer < 2) k_remap<<<EG, 256, 0, stream>>>(esrc, edst, ew, mapping);
        k_readout_comb<<<B_GRAPHS, 128, 0, stream>>>(pmax, psum, accum, k);

        xin = (const void*)XPbuf;
        npg = k;
        F = NHID;
        if (layer == 0) { Hbuf = bufB; Xbuf = bufA; XPbuf = bufB; }
        else            { Hbuf = bufA; Xbuf = bufB; XPbuf = bufA; }
    }

    k_final<<<B_GRAPHS, 128, 0, stream>>>(accum, Wl, bl, out);
}

// Round 4
// 684.090 us; speedup vs baseline: 2.7929x; 1.0781x over previous
//
#include <hip/hip_runtime.h>
#include <math.h>

#define B_GRAPHS 50
#define NPG0     2000
#define EPG      12000
#define F_IN_C   256
#define NHID     128
#define N0       (B_GRAPHS * NPG0)   // 100000
#define NE       (B_GRAPHS * EPG)    // 600000
#define RSEG     16                  // readout segments per graph
#define GSLOTS   7                   // ceil(50 graphs / 8 XCDs)

typedef _Float16 f16x8 __attribute__((ext_vector_type(8)));
typedef _Float16 f16x2 __attribute__((ext_vector_type(2)));
typedef float    f32x4 __attribute__((ext_vector_type(4)));

static inline int cdiv(int a, int b) { return (a + b - 1) / b; }

// ---------------- utility fills ----------------
__global__ void k_fill_f32(float* __restrict__ p, float v, int n) {
    int i = blockIdx.x * 256 + threadIdx.x;
    if (i < n) p[i] = v;
}
// zero cnt, optionally fill mapping with -1, in one launch
__global__ void k_fill2(int* __restrict__ cnt, int* __restrict__ mapping, int n, int do_map) {
    int i = blockIdx.x * 256 + threadIdx.x;
    if (i < n) {
        cnt[i] = 0;
        if (do_map) mapping[i] = -1;
    }
}

// ---------------- edge init ----------------
__global__ void k_init_edges(const int* __restrict__ ei, int* __restrict__ esrc,
                             int* __restrict__ edst, float* __restrict__ ew) {
    int e = blockIdx.x * 256 + threadIdx.x;
    if (e < NE) { esrc[e] = ei[e]; edst[e] = ei[NE + e]; ew[e] = 1.0f; }
}

// ---------------- weight convert+transpose: WT[n][k] = (fp16)W[k][n] ----------------
__global__ void k_cvt_wt(const float* __restrict__ W, _Float16* __restrict__ WT, int F) {
    int t = blockIdx.x * 256 + threadIdx.x;
    if (t >= F * 128) return;
    int n = t / F, kk = t - n * F;
    WT[t] = (_Float16)W[(size_t)kk * 128 + n];
}

// ---------------- MFMA GEMM: H[N x 128](fp16) = Xin[N x F] @ W[F x 128] ----------------
#define LDK  40
#define CPAD 136
template<int FP32IN>
__global__ __launch_bounds__(256) void k_gemm_mfma(const void* __restrict__ Xin,
                                                   const _Float16* __restrict__ WT,
                                                   _Float16* __restrict__ H,
                                                   int N, int F) {
    __shared__ _Float16 smem[17408];
    _Float16* sA  = smem;                 // [128][LDK]
    _Float16* sBT = smem + 128 * LDK;     // [128][LDK]
    const int tid  = threadIdx.x;
    const int wave = tid >> 6, lane = tid & 63;
    const int quad = lane >> 4, l16 = lane & 15;
    const int m_blk = blockIdx.x * 128;

    f32x4 acc[2][8];
#pragma unroll
    for (int i = 0; i < 2; ++i)
#pragma unroll
        for (int j = 0; j < 8; ++j) acc[i][j] = {0.f, 0.f, 0.f, 0.f};

    const int r  = tid >> 1;
    const int ch = (tid & 1) * 16;
    const int grow = m_blk + r;
    const int rw = wave * 32;

    for (int k0 = 0; k0 < F; k0 += 32) {
        f16x8 a0 = {0,0,0,0,0,0,0,0}, a1 = {0,0,0,0,0,0,0,0};
        if (grow < N) {
            if (FP32IN) {
                const float4* Xr = (const float4*)((const float*)Xin + (size_t)grow * F + k0 + ch);
                float4 f0 = Xr[0], f1 = Xr[1], f2 = Xr[2], f3 = Xr[3];
                a0 = (f16x8){(_Float16)f0.x,(_Float16)f0.y,(_Float16)f0.z,(_Float16)f0.w,
                             (_Float16)f1.x,(_Float16)f1.y,(_Float16)f1.z,(_Float16)f1.w};
                a1 = (f16x8){(_Float16)f2.x,(_Float16)f2.y,(_Float16)f2.z,(_Float16)f2.w,
                             (_Float16)f3.x,(_Float16)f3.y,(_Float16)f3.z,(_Float16)f3.w};
            } else {
                const f16x8* Xr = (const f16x8*)((const _Float16*)Xin + (size_t)grow * F + k0 + ch);
                a0 = Xr[0]; a1 = Xr[1];
            }
        }
        *(f16x8*)&sA[r * LDK + ch]     = a0;
        *(f16x8*)&sA[r * LDK + ch + 8] = a1;
        {
            const f16x8* Wr = (const f16x8*)(WT + (size_t)r * F + k0 + ch);
            *(f16x8*)&sBT[r * LDK + ch]     = Wr[0];
            *(f16x8*)&sBT[r * LDK + ch + 8] = Wr[1];
        }
        __syncthreads();
        f16x8 af0 = *(const f16x8*)&sA[(rw + l16) * LDK + quad * 8];
        f16x8 af1 = *(const f16x8*)&sA[(rw + 16 + l16) * LDK + quad * 8];
        f16x8 bf[8];
#pragma unroll
        for (int j = 0; j < 8; ++j)
            bf[j] = *(const f16x8*)&sBT[(j * 16 + l16) * LDK + quad * 8];
#pragma unroll
        for (int j = 0; j < 8; ++j) {
            acc[0][j] = __builtin_amdgcn_mfma_f32_16x16x32_f16(af0, bf[j], acc[0][j], 0, 0, 0);
            acc[1][j] = __builtin_amdgcn_mfma_f32_16x16x32_f16(af1, bf[j], acc[1][j], 0, 0, 0);
        }
        __syncthreads();
    }

    _Float16* sC = smem;                  // [128][CPAD]
#pragma unroll
    for (int i = 0; i < 2; ++i)
#pragma unroll
        for (int j = 0; j < 8; ++j)
#pragma unroll
            for (int g = 0; g < 4; ++g) {
                int rl = rw + i * 16 + quad * 4 + g;
                int cl = j * 16 + l16;
                sC[rl * CPAD + cl] = (_Float16)acc[i][j][g];
            }
    __syncthreads();
    {
        int rr = tid >> 1;
        int gr = m_blk + rr;
        if (gr < N) {
            _Float16* Hr = H + (size_t)gr * 128 + (tid & 1) * 64;
            const _Float16* Sr = sC + rr * CPAD + (tid & 1) * 64;
#pragma unroll
            for (int c = 0; c < 8; ++c)
                *(f16x8*)&Hr[c * 8] = *(const f16x8*)&Sr[c * 8];
        }
    }
}

// ---------------- CSR build (w is always 0 or 1 -> deg = cnt+1) ----------------
__global__ void k_count(const int* __restrict__ edst, const float* __restrict__ ew,
                        int* __restrict__ cnt) {
    int e = blockIdx.x * 256 + threadIdx.x;
    if (e < NE) {
        if (ew[e] > 0.f) atomicAdd(&cnt[edst[e]], 1);
    }
}

__global__ __launch_bounds__(256) void k_scan(const int* __restrict__ cnt,
                                              int* __restrict__ offs,
                                              int* __restrict__ cursor, int npg) {
    __shared__ int ch[256];
    int b = blockIdx.x, tid = threadIdx.x;
    int per = (npg + 255) >> 8;
    int base = b * npg;
    int s0 = tid * per;
    int s1 = s0 + per; if (s1 > npg) s1 = npg; if (s0 > npg) s0 = npg;
    int s = 0;
    for (int i = s0; i < s1; ++i) s += cnt[base + i];
    ch[tid] = s;
    __syncthreads();
    for (int d = 1; d < 256; d <<= 1) {
        int t = ch[tid] + ((tid >= d) ? ch[tid - d] : 0);
        __syncthreads();
        ch[tid] = t;
        __syncthreads();
    }
    int run = b * EPG + ch[tid] - s;
    for (int i = s0; i < s1; ++i) {
        offs[base + i] = run; cursor[base + i] = run;
        run += cnt[base + i];
    }
}

__global__ void k_fill_csr(const int* __restrict__ esrc, const int* __restrict__ edst,
                           const float* __restrict__ ew, const int* __restrict__ cnt,
                           int* __restrict__ cursor, int* __restrict__ csr_src,
                           float* __restrict__ csr_norm) {
    int e = blockIdx.x * 256 + threadIdx.x;
    if (e < NE) {
        if (ew[e] > 0.f) {
            int sN = esrc[e], d = edst[e];
            int pos = atomicAdd(&cursor[d], 1);
            csr_src[pos] = sN;
            csr_norm[pos] = rsqrtf((float)(cnt[sN] + 1)) * rsqrtf((float)(cnt[d] + 1));
        }
    }
}

// -------- aggregation + fused score projection, 4-edge ILP + XCD swizzle --------
// 1 wave per node, 4 waves/block. quad q handles edges e0+q; lane reads f16x8 (16B).
// blockIdx swizzled so graph g's blocks land at dispatch slots == g (mod 8) -> same XCD L2.
__global__ __launch_bounds__(256) void k_agg(const _Float16* __restrict__ H,
                                             const int* __restrict__ csr_src,
                                             const float* __restrict__ csr_norm,
                                             const int* __restrict__ offs,
                                             const int* __restrict__ cnt,
                                             const float* __restrict__ bias,
                                             const float* __restrict__ Ws,
                                             _Float16* __restrict__ X,
                                             float* __restrict__ hs,
                                             int bpg, int npg) {
    int bi = blockIdx.x;
    int x = bi & 7, s = bi >> 3;
    int gslot = s / bpg, blk = s - gslot * bpg;
    int g = x + 8 * gslot;
    if (g >= B_GRAPHS) return;
    int node = g * npg + blk * 4 + (threadIdx.x >> 6);
    int lane = threadIdx.x & 63;
    int quad = lane >> 4, l16 = lane & 15;

    int st = offs[node], c = cnt[node], en = st + c;
    float acc[8];
#pragma unroll
    for (int j = 0; j < 8; ++j) acc[j] = 0.f;

    for (int e0 = st; e0 < en; e0 += 4) {
        int e = e0 + quad;
        if (e < en) {
            int u = csr_src[e];
            float nrm = csr_norm[e];
            f16x8 h = *(const f16x8*)&H[(size_t)u * NHID + l16 * 8];
#pragma unroll
            for (int j = 0; j < 8; ++j) acc[j] = fmaf((float)h[j], nrm, acc[j]);
        }
    }
    // combine the 4 quads (feature-aligned at fixed l16)
#pragma unroll
    for (int j = 0; j < 8; ++j) {
        acc[j] += __shfl_xor(acc[j], 16, 64);
        acc[j] += __shfl_xor(acc[j], 32, 64);
    }
    float invd = 1.f / (float)(c + 1);
    f16x8 hn = *(const f16x8*)&H[(size_t)node * NHID + l16 * 8];
    float4 b0 = *(const float4*)&bias[l16 * 8];
    float4 b1 = *(const float4*)&bias[l16 * 8 + 4];
    float4 w0 = *(const float4*)&Ws[l16 * 8];
    float4 w1 = *(const float4*)&Ws[l16 * 8 + 4];
    const float bb[8] = {b0.x, b0.y, b0.z, b0.w, b1.x, b1.y, b1.z, b1.w};
    const float ww[8] = {w0.x, w0.y, w0.z, w0.w, w1.x, w1.y, w1.z, w1.w};
    float sd = 0.f;
    f16x8 o;
#pragma unroll
    for (int j = 0; j < 8; ++j) {
        float v = fmaxf(acc[j] + (float)hn[j] * invd + bb[j], 0.f);
        o[j] = (_Float16)v;
        sd = fmaf(v, ww[j], sd);
    }
    if (quad == 0)
        *(f16x8*)&X[(size_t)node * NHID + l16 * 8] = o;
    // reduce sd over the 16 lanes (replicated across quads)
    sd += __shfl_xor(sd, 1, 64);
    sd += __shfl_xor(sd, 2, 64);
    sd += __shfl_xor(sd, 4, 64);
    sd += __shfl_xor(sd, 8, 64);
    if (lane == 0) hs[node] = sd;
}

// ---------------- score aggregation (scalar GCN) ----------------
__global__ void k_score(const float* __restrict__ hs, const int* __restrict__ csr_src,
                        const float* __restrict__ csr_norm, const int* __restrict__ offs,
                        const int* __restrict__ cnt, const float* __restrict__ bs,
                        float* __restrict__ score, int N) {
    int i = blockIdx.x * 256 + threadIdx.x;
    if (i >= N) return;
    int s = offs[i], c = cnt[i];
    float a = 0.f;
    for (int e = s; e < s + c; ++e) a = fmaf(hs[csr_src[e]], csr_norm[e], a);
    score[i] = a + hs[i] / (float)(c + 1) + bs[0];
}

// ---------------- per-graph top-k via bitonic sort (desc score, asc idx) ----------------
__global__ __launch_bounds__(1024) void k_topk(const float* __restrict__ score,
                                               int* __restrict__ mapping,
                                               int* __restrict__ perm,
                                               float* __restrict__ gate,
                                               int npg, int k) {
    __shared__ float ss[2048];
    __shared__ int   si[2048];
    int b = blockIdx.x, tid = threadIdx.x;
    for (int i = tid; i < 2048; i += 1024) {
        if (i < npg) { ss[i] = score[b * npg + i]; si[i] = i; }
        else         { ss[i] = -__builtin_inff();  si[i] = i; }
    }
    __syncthreads();
    for (int size = 2; size <= 2048; size <<= 1) {
        for (int stride = size >> 1; stride > 0; stride >>= 1) {
            int t = tid;
            int i = ((t & ~(stride - 1)) << 1) | (t & (stride - 1));
            int j = i | stride;
            float sa = ss[i], sb = ss[j];
            int   ia = si[i], ib = si[j];
            bool b_before_a = (sb > sa) || (sb == sa && ib < ia);
            bool forward = ((i & size) == 0);
            bool doswap = forward ? b_before_a : !b_before_a;
            if (doswap) { ss[i] = sb; ss[j] = sa; si[i] = ib; si[j] = ia; }
            __syncthreads();
        }
    }
    for (int j = tid; j < k; j += 1024) {
        int old_local = si[j];
        int oldg = b * npg + old_local;
        int newg = b * k + j;
        perm[newg] = oldg;
        mapping[oldg] = newg;
        gate[newg] = tanhf(ss[j]);
    }
}

// ---------------- fused pool + partial readout ----------------
__global__ __launch_bounds__(128) void k_pool_readout(const _Float16* __restrict__ X,
                                                      const float* __restrict__ gate,
                                                      const int* __restrict__ perm,
                                                      _Float16* __restrict__ XP,
                                                      float* __restrict__ pmax,
                                                      float* __restrict__ psum, int k) {
    int s = blockIdx.x, b = blockIdx.y, f = threadIdx.x;
    int j0 = (k * s) / RSEG, j1 = (k * (s + 1)) / RSEG;
    float mx = -__builtin_inff(), sm = 0.f;
    for (int j = j0; j < j1; ++j) {
        int g = b * k + j;
        int old = perm[g];
        float v = (float)X[(size_t)old * NHID + f] * gate[g];
        XP[(size_t)g * NHID + f] = (_Float16)v;
        mx = fmaxf(mx, v);
        sm += v;
    }
    pmax[(size_t)(b * RSEG + s) * NHID + f] = mx;
    psum[(size_t)(b * RSEG + s) * NHID + f] = sm;
}

__global__ __launch_bounds__(128) void k_readout_comb(const float* __restrict__ pmax,
                                                      const float* __restrict__ psum,
                                                      float* __restrict__ accum, int k) {
    int b = blockIdx.x, f = threadIdx.x;
    float mx = -__builtin_inff(), sm = 0.f;
#pragma unroll
    for (int s = 0; s < RSEG; ++s) {
        mx = fmaxf(mx, pmax[(size_t)(b * RSEG + s) * NHID + f]);
        sm += psum[(size_t)(b * RSEG + s) * NHID + f];
    }
    accum[b * 256 + f]       += mx;
    accum[b * 256 + 128 + f] += sm / (float)k;
}

// ---------------- edge remap (in place) ----------------
__global__ void k_remap(int* __restrict__ esrc, int* __restrict__ edst,
                        float* __restrict__ ew, const int* __restrict__ mapping) {
    int e = blockIdx.x * 256 + threadIdx.x;
    if (e >= NE) return;
    int sN = esrc[e], d = edst[e];
    float we = ew[e];
    int ns = mapping[sN], nd = mapping[d];
    bool valid = (ns >= 0) && (nd >= 0) && (we > 0.f);
    esrc[e] = valid ? ns : 0;
    edst[e] = valid ? nd : 0;
    ew[e] = valid ? we : 0.f;
}

// ---------------- final: out = relu(accum @ Wl + bl) ----------------
__global__ __launch_bounds__(128) void k_final(const float* __restrict__ accum,
                                               const float* __restrict__ Wl,
                                               const float* __restrict__ bl,
                                               float* __restrict__ out) {
    __shared__ float a[256];
    int b = blockIdx.x, o = threadIdx.x;
    for (int i = o; i < 256; i += 128) a[i] = accum[b * 256 + i];
    __syncthreads();
    float s = bl[o];
    for (int i = 0; i < 256; ++i) s = fmaf(a[i], Wl[i * NHID + o], s);
    out[b * NHID + o] = fmaxf(s, 0.f);
}

extern "C" void kernel_launch(void* const* d_in, const int* in_sizes, int n_in,
                              void* d_out, int out_size, void* d_ws, size_t ws_size,
                              hipStream_t stream) {
    const float* x0 = (const float*)d_in[0];
    const float* Wm[3] = {(const float*)d_in[1], (const float*)d_in[5], (const float*)d_in[9]};
    const float* bm[3] = {(const float*)d_in[2], (const float*)d_in[6], (const float*)d_in[10]};
    const float* Wsc[3] = {(const float*)d_in[3], (const float*)d_in[7], (const float*)d_in[11]};
    const float* bsc[3] = {(const float*)d_in[4], (const float*)d_in[8], (const float*)d_in[12]};
    const float* Wl = (const float*)d_in[13];
    const float* bl = (const float*)d_in[14];
    const int*   ei = (const int*)d_in[15];
    float* out = (float*)d_out;

    _Float16* bufA = (_Float16*)d_ws;                       // N0*128 halves
    _Float16* bufB = bufA + (size_t)N0 * NHID;              // N0*128
    _Float16* WT1  = bufB + (size_t)N0 * NHID;              // 128*256
    _Float16* WT2  = WT1 + 128 * 256;                       // 128*128
    _Float16* WT3  = WT2 + 128 * 128;                       // 128*128
    float* hs     = (float*)(WT3 + 128 * 128);              // N0
    float* score  = hs + N0;                                // N0
    float* gate   = score + N0;                             // N0
    float* accum  = gate + N0;                              // B*256
    float* pmax   = accum + B_GRAPHS * 256;                 // B*RSEG*128
    float* psum   = pmax + B_GRAPHS * RSEG * NHID;          // B*RSEG*128
    int*   cnt    = (int*)(psum + B_GRAPHS * RSEG * NHID);  // N0
    int*   offs   = cnt + N0;                               // N0
    int*   cursor = offs + N0;                              // N0
    int*   mapping= cursor + N0;                            // N0
    int*   perm   = mapping + N0;                           // N0
    int*   esrc   = perm + N0;                              // NE
    int*   edst   = esrc + NE;                              // NE
    float* ew     = (float*)(edst + NE);                    // NE
    int*   csr_src= (int*)(ew + NE);                        // NE
    float* csr_norm = (float*)(csr_src + NE);               // NE

    _Float16* WTs[3] = {WT1, WT2, WT3};
    const int EG = cdiv(NE, 256);

    k_init_edges<<<EG, 256, 0, stream>>>(ei, esrc, edst, ew);
    k_fill_f32<<<cdiv(B_GRAPHS * 256, 256), 256, 0, stream>>>(accum, 0.f, B_GRAPHS * 256);
    k_cvt_wt<<<cdiv(256 * 128, 256), 256, 0, stream>>>(Wm[0], WT1, 256);
    k_cvt_wt<<<cdiv(128 * 128, 256), 256, 0, stream>>>(Wm[1], WT2, 128);
    k_cvt_wt<<<cdiv(128 * 128, 256), 256, 0, stream>>>(Wm[2], WT3, 128);

    int npg = NPG0;
    const void* xin = (const void*)x0;
    int F = F_IN_C;
    _Float16* Hbuf = bufA; _Float16* Xbuf = bufB; _Float16* XPbuf = bufA;

    for (int layer = 0; layer < 3; ++layer) {
        int N = B_GRAPHS * npg;
        int k = (npg * 4) / 5;   // ceil(0.8*n) exact for 2000/1600/1280
        int NG = cdiv(N, 256);
        int bpg = npg >> 2;      // blocks per graph in k_agg (npg divisible by 4)

        k_fill2<<<NG, 256, 0, stream>>>(cnt, mapping, N, layer < 2 ? 1 : 0);

        if (layer == 0)
            k_gemm_mfma<1><<<cdiv(N, 128), 256, 0, stream>>>(xin, WTs[layer], Hbuf, N, F);
        else
            k_gemm_mfma<0><<<cdiv(N, 128), 256, 0, stream>>>(xin, WTs[layer], Hbuf, N, F);
        k_count<<<EG, 256, 0, stream>>>(edst, ew, cnt);
        k_scan<<<B_GRAPHS, 256, 0, stream>>>(cnt, offs, cursor, npg);
        k_fill_csr<<<EG, 256, 0, stream>>>(esrc, edst, ew, cnt, cursor, csr_src, csr_norm);
        k_agg<<<8 * GSLOTS * bpg, 256, 0, stream>>>(Hbuf, csr_src, csr_norm, offs, cnt,
                                                    bm[layer], Wsc[layer], Xbuf, hs, bpg, npg);
        k_score<<<NG, 256, 0, stream>>>(hs, csr_src, csr_norm, offs, cnt, bsc[layer], score, N);
        k_topk<<<B_GRAPHS, 1024, 0, stream>>>(score, mapping, perm, gate, npg, k);
        k_pool_readout<<<dim3(RSEG, B_GRAPHS), 128, 0, stream>>>(Xbuf, gate, perm, XPbuf, pmax, psum, k);
        if (layer < 2) k_remap<<<EG, 256, 0, stream>>>(esrc, edst, ew, mapping);
        k_readout_comb<<<B_GRAPHS, 128, 0, stream>>>(pmax, psum, accum, k);

        xin = (const void*)XPbuf;
        npg = k;
        F = NHID;
        if (layer == 0) { Hbuf = bufB; Xbuf = bufA; XPbuf = bufB; }
        else            { Hbuf = bufA; Xbuf = bufB; XPbuf = bufA; }
    }

    k_final<<<B_GRAPHS, 128, 0, stream>>>(accum, Wl, bl, out);
}

// Round 5
// 683.704 us; speedup vs baseline: 2.7945x; 1.0006x over previous
//
#include <hip/hip_runtime.h>
#include <math.h>

#define B_GRAPHS 50
#define NPG0     2000
#define EPG      12000
#define F_IN_C   256
#define NHID     128
#define N0       (B_GRAPHS * NPG0)   // 100000
#define NE       (B_GRAPHS * EPG)    // 600000
#define RSEG     16                  // readout segments per graph
#define GSLOTS   7                   // ceil(50 graphs / 8 XCDs)
#define CPAD     136

typedef _Float16 f16x8 __attribute__((ext_vector_type(8)));
typedef _Float16 f16x2 __attribute__((ext_vector_type(2)));
typedef float    f32x4 __attribute__((ext_vector_type(4)));

static inline int cdiv(int a, int b) { return (a + b - 1) / b; }

// ---------------- utility fills ----------------
__global__ void k_fill_f32(float* __restrict__ p, float v, int n) {
    int i = blockIdx.x * 256 + threadIdx.x;
    if (i < n) p[i] = v;
}
__global__ void k_fill2(int* __restrict__ cnt, int* __restrict__ mapping, int n, int do_map) {
    int i = blockIdx.x * 256 + threadIdx.x;
    if (i < n) {
        cnt[i] = 0;
        if (do_map) mapping[i] = -1;
    }
}

// ---------------- edge init ----------------
__global__ void k_init_edges(const int* __restrict__ ei, int* __restrict__ esrc,
                             int* __restrict__ edst, float* __restrict__ ew) {
    int e = blockIdx.x * 256 + threadIdx.x;
    if (e < NE) { esrc[e] = ei[e]; edst[e] = ei[NE + e]; ew[e] = 1.0f; }
}

// ---------------- weight convert+transpose: WT[n][k] = (fp16)W[k][n] ----------------
__global__ void k_cvt_wt(const float* __restrict__ W, _Float16* __restrict__ WT, int F) {
    int t = blockIdx.x * 256 + threadIdx.x;
    if (t >= F * 128) return;
    int n = t / F, kk = t - n * F;
    WT[t] = (_Float16)W[(size_t)kk * 128 + n];
}

// ---------------- weight-stationary MFMA GEMM: H[N x 128](fp16) = Xin[N x F] @ W ----------------
// W^T staged in LDS ONCE (XOR-swizzled), then a barrier-free fully-unrolled K-loop:
// A fragments load global->register directly in MFMA layout. 256 thr = 4 waves, 128-row tile.
template<int FP32IN, int F>
__global__ __launch_bounds__(256) void k_gemm_ws(const void* __restrict__ Xin,
                                                 const _Float16* __restrict__ WT,
                                                 _Float16* __restrict__ H, int N) {
    constexpr int SMEMSZ = (F * 128 > 128 * CPAD) ? F * 128 : 128 * CPAD;
    __shared__ _Float16 smem[SMEMSZ];
    const int tid  = threadIdx.x;
    const int wave = tid >> 6, lane = tid & 63;
    const int quad = lane >> 4, l16 = lane & 15;
    const int m_blk = blockIdx.x * 128;

    // ---- stage full W^T[128][F] into LDS, chunk-XOR swizzle on k8 ----
    constexpr int K8 = F / 8;          // 16-B chunks per row
#pragma unroll
    for (int c = tid; c < 128 * K8; c += 256) {
        int n = c / K8, k8 = c - n * K8;
        f16x8 v = *(const f16x8*)&WT[(size_t)c * 8];
        *(f16x8*)&smem[n * F + ((k8 ^ (n & 7)) << 3)] = v;
    }
    __syncthreads();

    f32x4 acc[2][8];
#pragma unroll
    for (int i = 0; i < 2; ++i)
#pragma unroll
        for (int j = 0; j < 8; ++j) acc[i][j] = {0.f, 0.f, 0.f, 0.f};

    // A rows for this wave (clamped; stores are guarded so garbage rows are dropped)
    int row0 = m_blk + wave * 32 + l16;
    int row1 = row0 + 16;
    if (row0 > N - 1) row0 = N - 1;
    if (row1 > N - 1) row1 = N - 1;
    const int sx = l16 & 7;

#pragma unroll
    for (int kq = 0; kq < F / 32; ++kq) {
        f16x8 af0, af1;
        if (FP32IN) {
            const float4* X0 = (const float4*)((const float*)Xin + (size_t)row0 * F + kq * 32 + quad * 8);
            const float4* X1 = (const float4*)((const float*)Xin + (size_t)row1 * F + kq * 32 + quad * 8);
            float4 f0 = X0[0], f1 = X0[1], g0 = X1[0], g1 = X1[1];
            af0 = (f16x8){(_Float16)f0.x,(_Float16)f0.y,(_Float16)f0.z,(_Float16)f0.w,
                          (_Float16)f1.x,(_Float16)f1.y,(_Float16)f1.z,(_Float16)f1.w};
            af1 = (f16x8){(_Float16)g0.x,(_Float16)g0.y,(_Float16)g0.z,(_Float16)g0.w,
                          (_Float16)g1.x,(_Float16)g1.y,(_Float16)g1.z,(_Float16)g1.w};
        } else {
            af0 = *(const f16x8*)((const _Float16*)Xin + (size_t)row0 * F + kq * 32 + quad * 8);
            af1 = *(const f16x8*)((const _Float16*)Xin + (size_t)row1 * F + kq * 32 + quad * 8);
        }
        f16x8 bf[8];
#pragma unroll
        for (int j = 0; j < 8; ++j)
            bf[j] = *(const f16x8*)&smem[(j * 16 + l16) * F + ((((kq << 2) + quad) ^ sx) << 3)];
#pragma unroll
        for (int j = 0; j < 8; ++j) {
            acc[0][j] = __builtin_amdgcn_mfma_f32_16x16x32_f16(af0, bf[j], acc[0][j], 0, 0, 0);
            acc[1][j] = __builtin_amdgcn_mfma_f32_16x16x32_f16(af1, bf[j], acc[1][j], 0, 0, 0);
        }
    }
    __syncthreads();   // done reading W; reuse LDS for epilogue

    // ---- epilogue: bounce through LDS for coalesced fp16 stores ----
    _Float16* sC = smem;                  // [128][CPAD]
    const int rw = wave * 32;
#pragma unroll
    for (int i = 0; i < 2; ++i)
#pragma unroll
        for (int j = 0; j < 8; ++j)
#pragma unroll
            for (int g = 0; g < 4; ++g) {
                int rl = rw + i * 16 + quad * 4 + g;
                int cl = j * 16 + l16;
                sC[rl * CPAD + cl] = (_Float16)acc[i][j][g];
            }
    __syncthreads();
    {
        int rr = tid >> 1;
        int gr = m_blk + rr;
        if (gr < N) {
            _Float16* Hr = H + (size_t)gr * 128 + (tid & 1) * 64;
            const _Float16* Sr = sC + rr * CPAD + (tid & 1) * 64;
#pragma unroll
            for (int c = 0; c < 8; ++c)
                *(f16x8*)&Hr[c * 8] = *(const f16x8*)&Sr[c * 8];
        }
    }
}

// ---------------- CSR build (w is always 0 or 1 -> deg = cnt+1) ----------------
__global__ void k_count(const int* __restrict__ edst, const float* __restrict__ ew,
                        int* __restrict__ cnt) {
    int e = blockIdx.x * 256 + threadIdx.x;
    if (e < NE) {
        if (ew[e] > 0.f) atomicAdd(&cnt[edst[e]], 1);
    }
}

__global__ __launch_bounds__(256) void k_scan(const int* __restrict__ cnt,
                                              int* __restrict__ offs,
                                              int* __restrict__ cursor, int npg) {
    __shared__ int ch[256];
    int b = blockIdx.x, tid = threadIdx.x;
    int per = (npg + 255) >> 8;
    int base = b * npg;
    int s0 = tid * per;
    int s1 = s0 + per; if (s1 > npg) s1 = npg; if (s0 > npg) s0 = npg;
    int s = 0;
    for (int i = s0; i < s1; ++i) s += cnt[base + i];
    ch[tid] = s;
    __syncthreads();
    for (int d = 1; d < 256; d <<= 1) {
        int t = ch[tid] + ((tid >= d) ? ch[tid - d] : 0);
        __syncthreads();
        ch[tid] = t;
        __syncthreads();
    }
    int run = b * EPG + ch[tid] - s;
    for (int i = s0; i < s1; ++i) {
        offs[base + i] = run; cursor[base + i] = run;
        run += cnt[base + i];
    }
}

__global__ void k_fill_csr(const int* __restrict__ esrc, const int* __restrict__ edst,
                           const float* __restrict__ ew, const int* __restrict__ cnt,
                           int* __restrict__ cursor, int* __restrict__ csr_src,
                           float* __restrict__ csr_norm) {
    int e = blockIdx.x * 256 + threadIdx.x;
    if (e < NE) {
        if (ew[e] > 0.f) {
            int sN = esrc[e], d = edst[e];
            int pos = atomicAdd(&cursor[d], 1);
            csr_src[pos] = sN;
            csr_norm[pos] = rsqrtf((float)(cnt[sN] + 1)) * rsqrtf((float)(cnt[d] + 1));
        }
    }
}

// -------- aggregation + fused score projection, 4-edge ILP + XCD swizzle --------
__global__ __launch_bounds__(256) void k_agg(const _Float16* __restrict__ H,
                                             const int* __restrict__ csr_src,
                                             const float* __restrict__ csr_norm,
                                             const int* __restrict__ offs,
                                             const int* __restrict__ cnt,
                                             const float* __restrict__ bias,
                                             const float* __restrict__ Ws,
                                             _Float16* __restrict__ X,
                                             float* __restrict__ hs,
                                             int bpg, int npg) {
    int bi = blockIdx.x;
    int x = bi & 7, s = bi >> 3;
    int gslot = s / bpg, blk = s - gslot * bpg;
    int g = x + 8 * gslot;
    if (g >= B_GRAPHS) return;
    int node = g * npg + blk * 4 + (threadIdx.x >> 6);
    int lane = threadIdx.x & 63;
    int quad = lane >> 4, l16 = lane & 15;

    int st = offs[node], c = cnt[node], en = st + c;
    float acc[8];
#pragma unroll
    for (int j = 0; j < 8; ++j) acc[j] = 0.f;

    for (int e0 = st; e0 < en; e0 += 4) {
        int e = e0 + quad;
        if (e < en) {
            int u = csr_src[e];
            float nrm = csr_norm[e];
            f16x8 h = *(const f16x8*)&H[(size_t)u * NHID + l16 * 8];
#pragma unroll
            for (int j = 0; j < 8; ++j) acc[j] = fmaf((float)h[j], nrm, acc[j]);
        }
    }
#pragma unroll
    for (int j = 0; j < 8; ++j) {
        acc[j] += __shfl_xor(acc[j], 16, 64);
        acc[j] += __shfl_xor(acc[j], 32, 64);
    }
    float invd = 1.f / (float)(c + 1);
    f16x8 hn = *(const f16x8*)&H[(size_t)node * NHID + l16 * 8];
    float4 b0 = *(const float4*)&bias[l16 * 8];
    float4 b1 = *(const float4*)&bias[l16 * 8 + 4];
    float4 w0 = *(const float4*)&Ws[l16 * 8];
    float4 w1 = *(const float4*)&Ws[l16 * 8 + 4];
    const float bb[8] = {b0.x, b0.y, b0.z, b0.w, b1.x, b1.y, b1.z, b1.w};
    const float ww[8] = {w0.x, w0.y, w0.z, w0.w, w1.x, w1.y, w1.z, w1.w};
    float sd = 0.f;
    f16x8 o;
#pragma unroll
    for (int j = 0; j < 8; ++j) {
        float v = fmaxf(acc[j] + (float)hn[j] * invd + bb[j], 0.f);
        o[j] = (_Float16)v;
        sd = fmaf(v, ww[j], sd);
    }
    if (quad == 0)
        *(f16x8*)&X[(size_t)node * NHID + l16 * 8] = o;
    sd += __shfl_xor(sd, 1, 64);
    sd += __shfl_xor(sd, 2, 64);
    sd += __shfl_xor(sd, 4, 64);
    sd += __shfl_xor(sd, 8, 64);
    if (lane == 0) hs[node] = sd;
}

// ---------------- score aggregation (scalar GCN) ----------------
__global__ void k_score(const float* __restrict__ hs, const int* __restrict__ csr_src,
                        const float* __restrict__ csr_norm, const int* __restrict__ offs,
                        const int* __restrict__ cnt, const float* __restrict__ bs,
                        float* __restrict__ score, int N) {
    int i = blockIdx.x * 256 + threadIdx.x;
    if (i >= N) return;
    int s = offs[i], c = cnt[i];
    float a = 0.f;
    for (int e = s; e < s + c; ++e) a = fmaf(hs[csr_src[e]], csr_norm[e], a);
    score[i] = a + hs[i] / (float)(c + 1) + bs[0];
}

// ---------------- per-graph top-k via bitonic sort (desc score, asc idx) ----------------
__global__ __launch_bounds__(1024) void k_topk(const float* __restrict__ score,
                                               int* __restrict__ mapping,
                                               int* __restrict__ perm,
                                               float* __restrict__ gate,
                                               int npg, int k) {
    __shared__ float ss[2048];
    __shared__ int   si[2048];
    int b = blockIdx.x, tid = threadIdx.x;
    for (int i = tid; i < 2048; i += 1024) {
        if (i < npg) { ss[i] = score[b * npg + i]; si[i] = i; }
        else         { ss[i] = -__builtin_inff();  si[i] = i; }
    }
    __syncthreads();
    for (int size = 2; size <= 2048; size <<= 1) {
        for (int stride = size >> 1; stride > 0; stride >>= 1) {
            int t = tid;
            int i = ((t & ~(stride - 1)) << 1) | (t & (stride - 1));
            int j = i | stride;
            float sa = ss[i], sb = ss[j];
            int   ia = si[i], ib = si[j];
            bool b_before_a = (sb > sa) || (sb == sa && ib < ia);
            bool forward = ((i & size) == 0);
            bool doswap = forward ? b_before_a : !b_before_a;
            if (doswap) { ss[i] = sb; ss[j] = sa; si[i] = ib; si[j] = ia; }
            __syncthreads();
        }
    }
    for (int j = tid; j < k; j += 1024) {
        int old_local = si[j];
        int oldg = b * npg + old_local;
        int newg = b * k + j;
        perm[newg] = oldg;
        mapping[oldg] = newg;
        gate[newg] = tanhf(ss[j]);
    }
}

// ---------------- fused pool + partial readout ----------------
__global__ __launch_bounds__(128) void k_pool_readout(const _Float16* __restrict__ X,
                                                      const float* __restrict__ gate,
                                                      const int* __restrict__ perm,
                                                      _Float16* __restrict__ XP,
                                                      float* __restrict__ pmax,
                                                      float* __restrict__ psum, int k) {
    int s = blockIdx.x, b = blockIdx.y, f = threadIdx.x;
    int j0 = (k * s) / RSEG, j1 = (k * (s + 1)) / RSEG;
    float mx = -__builtin_inff(), sm = 0.f;
    for (int j = j0; j < j1; ++j) {
        int g = b * k + j;
        int old = perm[g];
        float v = (float)X[(size_t)old * NHID + f] * gate[g];
        XP[(size_t)g * NHID + f] = (_Float16)v;
        mx = fmaxf(mx, v);
        sm += v;
    }
    pmax[(size_t)(b * RSEG + s) * NHID + f] = mx;
    psum[(size_t)(b * RSEG + s) * NHID + f] = sm;
}

__global__ __launch_bounds__(128) void k_readout_comb(const float* __restrict__ pmax,
                                                      const float* __restrict__ psum,
                                                      float* __restrict__ accum, int k) {
    int b = blockIdx.x, f = threadIdx.x;
    float mx = -__builtin_inff(), sm = 0.f;
#pragma unroll
    for (int s = 0; s < RSEG; ++s) {
        mx = fmaxf(mx, pmax[(size_t)(b * RSEG + s) * NHID + f]);
        sm += psum[(size_t)(b * RSEG + s) * NHID + f];
    }
    accum[b * 256 + f]       += mx;
    accum[b * 256 + 128 + f] += sm / (float)k;
}

// ---------------- edge remap (in place) ----------------
__global__ void k_remap(int* __restrict__ esrc, int* __restrict__ edst,
                        float* __restrict__ ew, const int* __restrict__ mapping) {
    int e = blockIdx.x * 256 + threadIdx.x;
    if (e >= NE) return;
    int sN = esrc[e], d = edst[e];
    float we = ew[e];
    int ns = mapping[sN], nd = mapping[d];
    bool valid = (ns >= 0) && (nd >= 0) && (we > 0.f);
    esrc[e] = valid ? ns : 0;
    edst[e] = valid ? nd : 0;
    ew[e] = valid ? we : 0.f;
}

// ---------------- final: out = relu(accum @ Wl + bl) ----------------
__global__ __launch_bounds__(128) void k_final(const float* __restrict__ accum,
                                               const float* __restrict__ Wl,
                                               const float* __restrict__ bl,
                                               float* __restrict__ out) {
    __shared__ float a[256];
    int b = blockIdx.x, o = threadIdx.x;
    for (int i = o; i < 256; i += 128) a[i] = accum[b * 256 + i];
    __syncthreads();
    float s = bl[o];
    for (int i = 0; i < 256; ++i) s = fmaf(a[i], Wl[i * NHID + o], s);
    out[b * NHID + o] = fmaxf(s, 0.f);
}

extern "C" void kernel_launch(void* const* d_in, const int* in_sizes, int n_in,
                              void* d_out, int out_size, void* d_ws, size_t ws_size,
                              hipStream_t stream) {
    const float* x0 = (const float*)d_in[0];
    const float* Wm[3] = {(const float*)d_in[1], (const float*)d_in[5], (const float*)d_in[9]};
    const float* bm[3] = {(const float*)d_in[2], (const float*)d_in[6], (const float*)d_in[10]};
    const float* Wsc[3] = {(const float*)d_in[3], (const float*)d_in[7], (const float*)d_in[11]};
    const float* bsc[3] = {(const float*)d_in[4], (const float*)d_in[8], (const float*)d_in[12]};
    const float* Wl = (const float*)d_in[13];
    const float* bl = (const float*)d_in[14];
    const int*   ei = (const int*)d_in[15];
    float* out = (float*)d_out;

    _Float16* bufA = (_Float16*)d_ws;                       // N0*128 halves
    _Float16* bufB = bufA + (size_t)N0 * NHID;              // N0*128
    _Float16* WT1  = bufB + (size_t)N0 * NHID;              // 128*256
    _Float16* WT2  = WT1 + 128 * 256;                       // 128*128
    _Float16* WT3  = WT2 + 128 * 128;                       // 128*128
    float* hs     = (float*)(WT3 + 128 * 128);              // N0
    float* score  = hs + N0;                                // N0
    float* gate   = score + N0;                             // N0
    float* accum  = gate + N0;                              // B*256
    float* pmax   = accum + B_GRAPHS * 256;                 // B*RSEG*128
    float* psum   = pmax + B_GRAPHS * RSEG * NHID;          // B*RSEG*128
    int*   cnt    = (int*)(psum + B_GRAPHS * RSEG * NHID);  // N0
    int*   offs   = cnt + N0;                               // N0
    int*   cursor = offs + N0;                              // N0
    int*   mapping= cursor + N0;                            // N0
    int*   perm   = mapping + N0;                           // N0
    int*   esrc   = perm + N0;                              // NE
    int*   edst   = esrc + NE;                              // NE
    float* ew     = (float*)(edst + NE);                    // NE
    int*   csr_src= (int*)(ew + NE);                        // NE
    float* csr_norm = (float*)(csr_src + NE);               // NE

    _Float16* WTs[3] = {WT1, WT2, WT3};
    const int EG = cdiv(NE, 256);

    k_init_edges<<<EG, 256, 0, stream>>>(ei, esrc, edst, ew);
    k_fill_f32<<<cdiv(B_GRAPHS * 256, 256), 256, 0, stream>>>(accum, 0.f, B_GRAPHS * 256);
    k_cvt_wt<<<cdiv(256 * 128, 256), 256, 0, stream>>>(Wm[0], WT1, 256);
    k_cvt_wt<<<cdiv(128 * 128, 256), 256, 0, stream>>>(Wm[1], WT2, 128);
    k_cvt_wt<<<cdiv(128 * 128, 256), 256, 0, stream>>>(Wm[2], WT3, 128);

    int npg = NPG0;
    const void* xin = (const void*)x0;
    _Float16* Hbuf = bufA; _Float16* Xbuf = bufB; _Float16* XPbuf = bufA;

    for (int layer = 0; layer < 3; ++layer) {
        int N = B_GRAPHS * npg;
        int k = (npg * 4) / 5;   // ceil(0.8*n) exact for 2000/1600/1280
        int NG = cdiv(N, 256);
        int bpg = npg >> 2;      // blocks per graph in k_agg

        k_fill2<<<NG, 256, 0, stream>>>(cnt, mapping, N, layer < 2 ? 1 : 0);

        if (layer == 0)
            k_gemm_ws<1, 256><<<cdiv(N, 128), 256, 0, stream>>>(xin, WTs[layer], Hbuf, N);
        else
            k_gemm_ws<0, 128><<<cdiv(N, 128), 256, 0, stream>>>(xin, WTs[layer], Hbuf, N);
        k_count<<<EG, 256, 0, stream>>>(edst, ew, cnt);
        k_scan<<<B_GRAPHS, 256, 0, stream>>>(cnt, offs, cursor, npg);
        k_fill_csr<<<EG, 256, 0, stream>>>(esrc, edst, ew, cnt, cursor, csr_src, csr_norm);
        k_agg<<<8 * GSLOTS * bpg, 256, 0, stream>>>(Hbuf, csr_src, csr_norm, offs, cnt,
                                                    bm[layer], Wsc[layer], Xbuf, hs, bpg, npg);
        k_score<<<NG, 256, 0, stream>>>(hs, csr_src, csr_norm, offs, cnt, bsc[layer], score, N);
        k_topk<<<B_GRAPHS, 1024, 0, stream>>>(score, mapping, perm, gate, npg, k);
        k_pool_readout<<<dim3(RSEG, B_GRAPHS), 128, 0, stream>>>(Xbuf, gate, perm, XPbuf, pmax, psum, k);
        if (layer < 2) k_remap<<<EG, 256, 0, stream>>>(esrc, edst, ew, mapping);
        k_readout_comb<<<B_GRAPHS, 128, 0, stream>>>(pmax, psum, accum, k);

        xin = (const void*)XPbuf;
        npg = k;
        if (layer == 0) { Hbuf = bufB; Xbuf = bufA; XPbuf = bufB; }
        else            { Hbuf = bufA; Xbuf = bufB; XPbuf = bufA; }
    }

    k_final<<<B_GRAPHS, 128, 0, stream>>>(accum, Wl, bl, out);
}